// Round 1
// baseline (8262.160 us; speedup 1.0000x reference)
//
#include <hip/hip_runtime.h>
#include <math.h>

#define SC_TOT   261888
#define T_CAT    4768
#define NWORDS   75
#define POST     1000
#define IMG_F    1024.0f
#define SCALE_CLAMP_F 4.135166556742356f

__device__ __forceinline__ unsigned ufloat(float f){
  unsigned b = __float_as_uint(f);
  return (b & 0x80000000u) ? ~b : (b | 0x80000000u);
}

__device__ const int d_aoff[5]   = {0, 196608, 245760, 258048, 261120};
__device__ const int d_M[5]      = {196608, 49152, 12288, 3072, 768};
__device__ const int d_K[5]      = {1000, 1000, 1000, 1000, 768};
__device__ const int d_catoff[5] = {0, 1000, 2000, 3000, 4000};

// -------------------- weight transpose: [o][c][9] -> [c][o][9] --------------------
__global__ void kwt(const float* __restrict__ w_conv, float* __restrict__ wt){
  int i = blockIdx.x*256 + threadIdx.x;
  if (i < 256*256*9){
    int k = i % 9; int rest = i / 9; int o = rest % 256; int c = rest / 256;
    wt[i] = w_conv[(o*256 + c)*9 + k];
  }
}

// -------------------- fused conv3x3 + relu + heads + box decode --------------------
template<int TP>
__global__ __launch_bounds__(256, 2) void kconv(
    const float* __restrict__ f, const float* __restrict__ wt, const float* __restrict__ b_conv,
    const float* __restrict__ w_obj, const float* __restrict__ b_obj,
    const float* __restrict__ w_delta, const float* __restrict__ b_delta,
    float* __restrict__ scores_ws, float* __restrict__ boxes_ws,
    int H, int W, int aoff, float fstride,
    float aw0, float aw1, float aw2, float ah0, float ah1, float ah2)
{
  constexpr int XSS = TP + 8;   // padded row stride for xs (16B aligned rows)
  constexpr int TLS = TP + 1;   // odd stride -> conflict-free
  __shared__ float xs[3*XSS];
  __shared__ float wlds[2304];
  __shared__ float t_lds[128*TLS];
  __shared__ float hb[16*TP];

  const int tid = threadIdx.x;
  const int w0 = blockIdx.x * TP;
  const int h  = blockIdx.y;
  const int n  = blockIdx.z;

  float acc[TP];
  #pragma unroll
  for (int p = 0; p < TP; p++) acc[p] = 0.f;

  const int o = tid;
  const long long fbase = (long long)n*256*H*W;
  const int NSTG = 3*(TP+2);
  int sdy = tid / (TP+2), sdx = tid % (TP+2);
  int sy = h - 1 + sdy, sx = w0 - 1 + sdx;
  bool sok = (tid < NSTG) && sy >= 0 && sy < H && sx >= 0 && sx < W;
  long long soff_i = (long long)sy*W + sx;

  for (int c = 0; c < 256; c++){
    if (tid < NSTG) xs[sdy*XSS + sdx] = sok ? f[fbase + (long long)c*H*W + soff_i] : 0.f;
    const float* wc = wt + c*2304;
    #pragma unroll
    for (int k = 0; k < 9; k++) wlds[tid + 256*k] = wc[tid + 256*k];
    __syncthreads();

    float wv[9];
    #pragma unroll
    for (int k = 0; k < 9; k++) wv[k] = wlds[o*9 + k];

    #pragma unroll
    for (int p0 = 0; p0 < TP; p0 += 16){
      #pragma unroll
      for (int dy = 0; dy < 3; dy++){
        const float* row = &xs[dy*XSS + p0];
        float xr[18];
        {
          float4 q0 = *(const float4*)(row);
          float4 q1 = *(const float4*)(row+4);
          float4 q2 = *(const float4*)(row+8);
          float4 q3 = *(const float4*)(row+12);
          xr[0]=q0.x; xr[1]=q0.y; xr[2]=q0.z; xr[3]=q0.w;
          xr[4]=q1.x; xr[5]=q1.y; xr[6]=q1.z; xr[7]=q1.w;
          xr[8]=q2.x; xr[9]=q2.y; xr[10]=q2.z; xr[11]=q2.w;
          xr[12]=q3.x; xr[13]=q3.y; xr[14]=q3.z; xr[15]=q3.w;
          xr[16]=row[16]; xr[17]=row[17];
        }
        float wa = wv[3*dy], wb = wv[3*dy+1], wcc = wv[3*dy+2];
        #pragma unroll
        for (int pp = 0; pp < 16; pp++)
          acc[p0+pp] += wa*xr[pp] + wb*xr[pp+1] + wcc*xr[pp+2];
      }
    }
    __syncthreads();
  }

  // bias + relu (acc now holds t[o][p])
  float bc = b_conv[o];
  #pragma unroll
  for (int p = 0; p < TP; p++){ float v = acc[p] + bc; acc[p] = v > 0.f ? v : 0.f; }

  // heads: 15 dot products of length 256 per pixel
  constexpr int G = 256 / TP;
  constexpr int HPT = (15 + G - 1) / G;
  const int p = tid & (TP-1);
  const int g = tid / TP;
  const float* wj[HPT];
  int jidx[HPT];
  float hacc[HPT];
  #pragma unroll
  for (int q = 0; q < HPT; q++){
    int j = g*HPT + q;
    jidx[q] = j;
    hacc[q] = 0.f;
    wj[q] = (j < 3) ? (w_obj + j*256) : ((j < 15) ? (w_delta + (j-3)*256) : w_obj);
  }
  for (int half = 0; half < 2; half++){
    __syncthreads();
    if ((tid >> 7) == half){
      int orow = tid & 127;
      #pragma unroll
      for (int pp = 0; pp < TP; pp++) t_lds[orow*TLS + pp] = acc[pp];
    }
    __syncthreads();
    for (int oo = 0; oo < 128; oo++){
      float tv = t_lds[oo*TLS + p];
      int ob = half*128 + oo;
      #pragma unroll
      for (int q = 0; q < HPT; q++) hacc[q] += wj[q][ob] * tv;
    }
  }
  #pragma unroll
  for (int q = 0; q < HPT; q++){
    int j = jidx[q];
    if (j < 15){
      float bias = (j < 3) ? b_obj[j] : b_delta[j-3];
      hb[j*TP + p] = hacc[q] + bias;
    }
  }
  __syncthreads();

  // box decode + clip + write
  if (tid < 3*TP){
    int a = tid % 3, pp = tid / 3;
    float score = hb[a*TP + pp];
    float dx  = hb[(3 + a*4 + 0)*TP + pp];
    float dyv = hb[(3 + a*4 + 1)*TP + pp];
    float dw  = hb[(3 + a*4 + 2)*TP + pp];
    float dh  = hb[(3 + a*4 + 3)*TP + pp];
    float aw = (a==0)?aw0:((a==1)?aw1:aw2);
    float ah = (a==0)?ah0:((a==1)?ah1:ah2);
    float gx = (float)(w0 + pp) * fstride;
    float gy = (float)h * fstride;
    float pcx = dx*aw + gx;
    float pcy = dyv*ah + gy;
    float pw = expf(fminf(dw, SCALE_CLAMP_F))*aw;
    float ph = expf(fminf(dh, SCALE_CLAMP_F))*ah;
    float x1 = pcx - 0.5f*pw, y1 = pcy - 0.5f*ph;
    float x2 = pcx + 0.5f*pw, y2 = pcy + 0.5f*ph;
    x1 = fminf(fmaxf(x1, 0.f), IMG_F); y1 = fminf(fmaxf(y1, 0.f), IMG_F);
    x2 = fminf(fmaxf(x2, 0.f), IMG_F); y2 = fminf(fmaxf(y2, 0.f), IMG_F);
    long long ai = (long long)n*SC_TOT + aoff + (long long)(h*W + w0 + pp)*3 + a;
    scores_ws[ai] = score;
    ((float4*)boxes_ws)[ai] = make_float4(x1, y1, x2, y2);
  }
}

// -------------------- zero scratch --------------------
__global__ void kzero(unsigned* ghist, int* cnts, int* meta){
  int i = blockIdx.x*256 + threadIdx.x;
  if (i < 4*10*256) ghist[i] = 0u;
  if (i < 32){ cnts[i] = 0; meta[i] = 0; }
}

// -------------------- radix-select histogram pass --------------------
__global__ __launch_bounds__(256) void khist(const float* __restrict__ scores_ws,
    unsigned* __restrict__ ghist, const int* __restrict__ meta, int pass)
{
  int seg = blockIdx.y; int img = seg/5, lvl = seg%5;
  int M = d_M[lvl];
  const float* sc = scores_ws + (long long)img*SC_TOT + d_aoff[lvl];
  __shared__ unsigned h[256];
  if (threadIdx.x < 256) h[threadIdx.x] = 0u;
  __syncthreads();
  int shift = 24 - 8*pass;
  unsigned prefix = (pass > 0) ? ((const unsigned*)meta)[seg*2] : 0u;
  unsigned pmask  = (pass > 0) ? (0xFFFFFFFFu << (shift+8)) : 0u;
  int chunk = (M + (int)gridDim.x - 1) / (int)gridDim.x;
  int lo = blockIdx.x*chunk, hiI = min(lo+chunk, M);
  for (int i = lo + threadIdx.x; i < hiI; i += 256){
    unsigned u = ufloat(sc[i]);
    if (((u ^ prefix) & pmask) == 0u) atomicAdd(&h[(u>>shift)&255u], 1u);
  }
  __syncthreads();
  unsigned* gh = ghist + (pass*10 + seg)*256;
  if (threadIdx.x < 256 && h[threadIdx.x]) atomicAdd(&gh[threadIdx.x], h[threadIdx.x]);
}

__global__ void kscan(const unsigned* __restrict__ ghist, int* meta, int pass){
  int seg = threadIdx.x;
  if (seg < 10){
    int lvl = seg % 5; int k = d_K[lvl];
    unsigned prefix = 0u; int rem = k;
    if (pass > 0){ prefix = ((unsigned*)meta)[seg*2]; rem = meta[seg*2+1]; }
    const unsigned* h = ghist + (pass*10+seg)*256;
    int shift = 24 - 8*pass;
    int r = rem; int b = 0;
    for (int x = 255; x >= 0; x--){
      int c = (int)h[x];
      if (c >= r){ b = x; break; }
      r -= c;
    }
    ((unsigned*)meta)[seg*2] = prefix | ((unsigned)b << shift);
    meta[seg*2+1] = r;
  }
}

// -------------------- selection (threshold from radix-select) --------------------
__global__ __launch_bounds__(256) void kselect(const float* __restrict__ scores_ws,
    const int* __restrict__ meta, unsigned long long* __restrict__ selg,
    unsigned* __restrict__ tieg, int* __restrict__ cnts)
{
  int seg = blockIdx.y; int img = seg/5, lvl = seg%5;
  int M = d_M[lvl];
  const float* sc = scores_ws + (long long)img*SC_TOT + d_aoff[lvl];
  unsigned ut = ((const unsigned*)meta)[seg*2];
  int chunk = (M + (int)gridDim.x - 1) / (int)gridDim.x;
  int lo = blockIdx.x*chunk, hiI = min(lo+chunk, M);
  for (int i = lo + threadIdx.x; i < hiI; i += 256){
    unsigned u = ufloat(sc[i]);
    if (u > ut){
      int pp = atomicAdd(&cnts[seg*2], 1);
      if (pp < 1024) selg[seg*1024 + pp] = ((unsigned long long)u << 32) | (unsigned)(~(unsigned)i);
    } else if (u == ut){
      int pp = atomicAdd(&cnts[seg*2+1], 1);
      if (pp < 1024) tieg[seg*1024 + pp] = (unsigned)i;
    }
  }
}

// -------------------- per-(img,lvl) sort of selected k --------------------
__device__ __forceinline__ void bitonic_u32_asc(unsigned* a, int tid){
  for (int k2 = 2; k2 <= 1024; k2 <<= 1)
    for (int j = k2>>1; j > 0; j >>= 1){
      int ixj = tid ^ j;
      if (ixj > tid){
        unsigned A = a[tid], B = a[ixj];
        bool up = ((tid & k2) == 0);
        if (up ? (A > B) : (A < B)){ a[tid] = B; a[ixj] = A; }
      }
      __syncthreads();
    }
}
__device__ __forceinline__ void bitonic_u64_desc(unsigned long long* a, int tid){
  for (int k2 = 2; k2 <= 1024; k2 <<= 1)
    for (int j = k2>>1; j > 0; j >>= 1){
      int ixj = tid ^ j;
      if (ixj > tid){
        unsigned long long A = a[tid], B = a[ixj];
        bool up = ((tid & k2) == 0);
        if (up ? (A < B) : (A > B)){ a[tid] = B; a[ixj] = A; }
      }
      __syncthreads();
    }
}

__global__ __launch_bounds__(1024) void ksort(const float* __restrict__ scores_ws,
    const float* __restrict__ boxes_ws, const unsigned long long* __restrict__ selg,
    const unsigned* __restrict__ tieg, const int* __restrict__ cnts, const int* __restrict__ meta,
    float* __restrict__ cat_scores, unsigned* __restrict__ cat_u, float* __restrict__ cat_boxes)
{
  int seg = blockIdx.x; int img = seg/5, lvl = seg%5;
  int k = d_K[lvl];
  unsigned ut = ((const unsigned*)meta)[seg*2];
  int cg = cnts[seg*2];
  int ct = min(cnts[seg*2+1], 1024);
  __shared__ unsigned long long sb[1024];
  __shared__ unsigned tb[1024];
  int tid = threadIdx.x;
  tb[tid] = (tid < ct) ? tieg[seg*1024 + tid] : 0xFFFFFFFFu;
  __syncthreads();
  bitonic_u32_asc(tb, tid);   // ties sorted by original index ascending
  unsigned long long v = 0ull;
  if (tid < cg && tid < 1024) v = selg[seg*1024 + tid];
  else if (tid >= cg && tid < k) v = ((unsigned long long)ut << 32) | (unsigned)(~tb[tid - cg]);
  sb[tid] = v;
  __syncthreads();
  bitonic_u64_desc(sb, tid);  // (score desc, index asc)
  if (tid < k){
    unsigned long long e = sb[tid];
    unsigned idx = ~(unsigned)e;
    unsigned u = (unsigned)(e >> 32);
    int pos = d_catoff[lvl] + tid;
    long long src = (long long)img*SC_TOT + d_aoff[lvl] + idx;
    cat_scores[img*T_CAT + pos] = scores_ws[src];
    cat_u[img*T_CAT + pos] = u;
    ((float4*)cat_boxes)[img*T_CAT + pos] = ((const float4*)boxes_ws)[src];
  }
}

// -------------------- stable global merge-rank (== stable argsort desc) --------------------
__device__ __forceinline__ int cnt_gt_desc(const unsigned* a, int len, unsigned u){
  int lo=0, hi=len;
  while (lo<hi){ int m=(lo+hi)>>1; if (a[m] > u) lo=m+1; else hi=m; }
  return lo;
}
__device__ __forceinline__ int cnt_ge_desc(const unsigned* a, int len, unsigned u){
  int lo=0, hi=len;
  while (lo<hi){ int m=(lo+hi)>>1; if (a[m] >= u) lo=m+1; else hi=m; }
  return lo;
}

__global__ void krank(const float* __restrict__ cat_scores, const unsigned* __restrict__ cat_u,
    const float* __restrict__ cat_boxes, float* __restrict__ sscore, float* __restrict__ sbox,
    float* __restrict__ soff, int* __restrict__ svalid)
{
  int img = blockIdx.y;
  int pos = blockIdx.x*256 + threadIdx.x;
  if (pos >= T_CAT) return;
  const unsigned* cu = cat_u + img*T_CAT;
  int lvl = pos / 1000; if (lvl > 4) lvl = 4;
  unsigned u = cu[pos];
  int rank = pos - d_catoff[lvl];
  #pragma unroll
  for (int l2 = 0; l2 < 5; l2++){
    if (l2 == lvl) continue;
    const unsigned* segp = cu + d_catoff[l2];
    int len = d_K[l2];
    rank += (l2 < lvl) ? cnt_ge_desc(segp, len, u) : cnt_gt_desc(segp, len, u);
  }
  float s = cat_scores[img*T_CAT + pos];
  float4 b = ((const float4*)cat_boxes)[img*T_CAT + pos];
  sscore[img*T_CAT + rank] = s;
  ((float4*)sbox)[img*T_CAT + rank] = b;
  float of = (float)lvl * (IMG_F + 1.0f);
  ((float4*)soff)[img*T_CAT + rank] = make_float4(b.x+of, b.y+of, b.z+of, b.w+of);
  svalid[img*T_CAT + rank] = ((b.z - b.x > 0.0f) && (b.w - b.y > 0.0f)) ? 1 : 0;
}

// -------------------- IoU suppression bitmask (idx>i baked in) --------------------
__global__ __launch_bounds__(256) void kiou(const float* __restrict__ soff,
    unsigned long long* __restrict__ mask)
{
  int rowt = blockIdx.x, img = blockIdx.y;
  int wv = threadIdx.x >> 6, lane = threadIdx.x & 63;
  const float4* sb4 = (const float4*)soff + (long long)img*T_CAT;
  for (int rr = 0; rr < 16; rr++){
    int row = rowt*64 + wv*16 + rr;
    if (row >= T_CAT) break;
    float4 rb = sb4[row];
    float rarea = (rb.z - rb.x)*(rb.w - rb.y);
    for (int w = 0; w < NWORDS; w++){
      int col = w*64 + lane;
      bool pred = false;
      if (col < T_CAT && col > row){
        float4 cb = sb4[col];
        float carea = (cb.z - cb.x)*(cb.w - cb.y);
        float ltx = fmaxf(rb.x, cb.x), lty = fmaxf(rb.y, cb.y);
        float rbx = fminf(rb.z, cb.z), rby = fminf(rb.w, cb.w);
        float wx = fmaxf(rbx - ltx, 0.f), wy = fmaxf(rby - lty, 0.f);
        float inter = wx*wy;
        float uni = rarea + carea - inter;
        float iou = (uni > 0.f) ? (inter/uni) : 0.f;
        pred = iou > 0.7f;
      }
      unsigned long long b = __ballot(pred);
      if (lane == 0) mask[((long long)img*T_CAT + row)*NWORDS + w] = b;
    }
  }
}

// -------------------- greedy scan + finalize --------------------
__global__ __launch_bounds__(256) void knms(const unsigned long long* __restrict__ mask,
    const int* __restrict__ svalid, const float* __restrict__ sscore,
    const float* __restrict__ sbox, float* __restrict__ out)
{
  int img = blockIdx.x; int tid = threadIdx.x;
  __shared__ unsigned long long keep[NWORDS];
  __shared__ unsigned long long curs;
  __shared__ unsigned long long keepv[NWORDS];
  __shared__ int pk[NWORDS], pu[NWORDS];
  __shared__ int Ktot;
  for (int i = tid; i < NWORDS; i += 256) keep[i] = ~0ull;
  __syncthreads();
  const unsigned long long* mk = mask + (long long)img*T_CAT*NWORDS;
  for (int w0 = 0; w0 < NWORDS; w0++){
    if (tid < 64){
      int row = w0*64 + tid;
      unsigned long long m = (row < T_CAT) ? mk[(long long)row*NWORDS + w0] : 0ull;
      unsigned long long cur = keep[w0];
      for (int l = 0; l < 64; l++){
        unsigned long long ml = __shfl(m, l);
        if ((cur >> l) & 1ull) cur &= ~ml;
      }
      if (tid == 0){ keep[w0] = cur; curs = cur; }
    }
    __syncthreads();
    unsigned long long cur = curs;
    for (int w = w0 + 1 + tid; w < NWORDS; w += 256){
      unsigned long long kw = keep[w];
      for (int l = 0; l < 64; l++){
        if ((cur >> l) & 1ull)
          kw &= ~mk[(long long)(w0*64 + l)*NWORDS + w];
      }
      keep[w] = kw;
    }
    __syncthreads();
  }
  // apply valid mask
  for (int w = tid; w < NWORDS; w += 256){
    unsigned long long pres = (w < NWORDS-1) ? ~0ull : ((1ull << (T_CAT - 64*(NWORDS-1))) - 1ull);
    unsigned long long vb = 0ull;
    int base = w*64;
    for (int l = 0; l < 64; l++){
      int i = base + l;
      if (i < T_CAT && svalid[img*T_CAT + i]) vb |= (1ull << l);
    }
    keepv[w] = keep[w] & pres & vb;
  }
  __syncthreads();
  if (tid == 0){
    int s = 0;
    for (int w = 0; w < NWORDS; w++){ pk[w] = s; s += __popcll(keepv[w]); }
    Ktot = s;
    int su = 0;
    for (int w = 0; w < NWORDS; w++){
      unsigned long long pres = (w < NWORDS-1) ? ~0ull : ((1ull<<32) - 1ull);
      pu[w] = su; su += __popcll(pres & ~keepv[w]);
    }
  }
  __syncthreads();
  int K = Ktot;
  for (int i = tid; i < T_CAT; i += 256){
    int w = i >> 6, l = i & 63;
    unsigned long long kvw = keepv[w];
    bool kept = (kvw >> l) & 1ull;
    unsigned long long low = (l == 0) ? 0ull : ((1ull << l) - 1ull);
    int slot;
    if (kept) slot = pk[w] + __popcll(kvw & low);
    else {
      unsigned long long pres = (w < NWORDS-1) ? ~0ull : ((1ull<<32) - 1ull);
      slot = K + pu[w] + __popcll(pres & ~kvw & low);
    }
    if (slot < POST){
      float4 b = ((const float4*)sbox)[img*T_CAT + i];
      ((float4*)out)[img*POST + slot] = b;
      out[2*POST*4 + img*POST + slot] = kept ? sscore[img*T_CAT + i] : -__builtin_huge_valf();
    }
  }
}

// -------------------- host --------------------
extern "C" void kernel_launch(void* const* d_in, const int* in_sizes, int n_in,
                              void* d_out, int out_size, void* d_ws, size_t ws_size,
                              hipStream_t stream)
{
  const float* feats[5];
  for (int i = 0; i < 5; i++) feats[i] = (const float*)d_in[i];
  const float* w_conv  = (const float*)d_in[5];
  const float* b_conv  = (const float*)d_in[6];
  const float* w_obj   = (const float*)d_in[7];
  const float* b_obj   = (const float*)d_in[8];
  const float* w_delta = (const float*)d_in[9];
  const float* b_delta = (const float*)d_in[10];

  char* ws = (char*)d_ws;
  size_t off = 0;
  auto alloc = [&](size_t bytes)->char*{ char* r = ws + off; off += (bytes + 255) & ~(size_t)255; return r; };
  float*    wt         = (float*)   alloc(256*256*9*4);
  float*    scores_ws  = (float*)   alloc((size_t)2*SC_TOT*4);
  float*    boxes_ws   = (float*)   alloc((size_t)2*SC_TOT*16);
  float*    cat_scores = (float*)   alloc((size_t)2*T_CAT*4);
  unsigned* cat_u      = (unsigned*)alloc((size_t)2*T_CAT*4);
  float*    cat_boxes  = (float*)   alloc((size_t)2*T_CAT*16);
  float*    sscore     = (float*)   alloc((size_t)2*T_CAT*4);
  float*    sbox       = (float*)   alloc((size_t)2*T_CAT*16);
  float*    soff_b     = (float*)   alloc((size_t)2*T_CAT*16);
  int*      svalid     = (int*)     alloc((size_t)2*T_CAT*4);
  unsigned long long* mask = (unsigned long long*)alloc((size_t)2*T_CAT*NWORDS*8);
  unsigned* ghist      = (unsigned*)alloc(4*10*256*4);
  int*      meta       = (int*)     alloc(256);
  unsigned long long* selg = (unsigned long long*)alloc(10*1024*8);
  unsigned* tieg       = (unsigned*)alloc(10*1024*4);
  int*      cnts       = (int*)     alloc(256);
  (void)ws_size; (void)in_sizes; (void)n_in; (void)out_size;

  kwt<<<(256*256*9 + 255)/256, 256, 0, stream>>>(w_conv, wt);
  kzero<<<40, 256, 0, stream>>>(ghist, cnts, meta);

  struct Lv { int H, W, TP, aoff; float size, stride; };
  static const Lv LV[5] = {
    {256,256,64, 0,      32.f,  4.f},
    {128,128,64, 196608, 64.f,  8.f},
    {64, 64, 64, 245760, 128.f, 16.f},
    {32, 32, 32, 258048, 256.f, 32.f},
    {16, 16, 16, 261120, 512.f, 64.f},
  };
  const float ratios[3] = {0.5f, 1.0f, 2.0f};
  for (int l = 0; l < 5; l++){
    float area = LV[l].size * LV[l].size;
    float aw[3], ah[3];
    for (int a = 0; a < 3; a++){ aw[a] = sqrtf(area / ratios[a]); ah[a] = aw[a] * ratios[a]; }
    dim3 grid(LV[l].W / LV[l].TP, LV[l].H, 2);
    if (LV[l].TP == 64)
      kconv<64><<<grid, 256, 0, stream>>>(feats[l], wt, b_conv, w_obj, b_obj, w_delta, b_delta,
        scores_ws, boxes_ws, LV[l].H, LV[l].W, LV[l].aoff, LV[l].stride,
        aw[0],aw[1],aw[2], ah[0],ah[1],ah[2]);
    else if (LV[l].TP == 32)
      kconv<32><<<grid, 256, 0, stream>>>(feats[l], wt, b_conv, w_obj, b_obj, w_delta, b_delta,
        scores_ws, boxes_ws, LV[l].H, LV[l].W, LV[l].aoff, LV[l].stride,
        aw[0],aw[1],aw[2], ah[0],ah[1],ah[2]);
    else
      kconv<16><<<grid, 256, 0, stream>>>(feats[l], wt, b_conv, w_obj, b_obj, w_delta, b_delta,
        scores_ws, boxes_ws, LV[l].H, LV[l].W, LV[l].aoff, LV[l].stride,
        aw[0],aw[1],aw[2], ah[0],ah[1],ah[2]);
  }

  for (int pass = 0; pass < 4; pass++){
    khist<<<dim3(32,10), 256, 0, stream>>>(scores_ws, ghist, meta, pass);
    kscan<<<1, 64, 0, stream>>>(ghist, meta, pass);
  }
  kselect<<<dim3(32,10), 256, 0, stream>>>(scores_ws, meta, selg, tieg, cnts);
  ksort<<<10, 1024, 0, stream>>>(scores_ws, boxes_ws, selg, tieg, cnts, meta,
                                 cat_scores, cat_u, cat_boxes);
  krank<<<dim3((T_CAT+255)/256, 2), 256, 0, stream>>>(cat_scores, cat_u, cat_boxes,
                                                      sscore, sbox, soff_b, svalid);
  kiou<<<dim3(NWORDS, 2), 256, 0, stream>>>(soff_b, mask);
  knms<<<2, 256, 0, stream>>>(mask, svalid, sscore, sbox, (float*)d_out);
}

// Round 2
// 6483.931 us; speedup vs baseline: 1.2743x; 1.2743x over previous
//
#include <hip/hip_runtime.h>
#include <math.h>

#define SC_TOT   261888
#define T_CAT    4768
#define NWORDS   75
#define POST     1000
#define IMG_F    1024.0f
#define SCALE_CLAMP_F 4.135166556742356f

__device__ __forceinline__ unsigned ufloat(float f){
  unsigned b = __float_as_uint(f);
  return (b & 0x80000000u) ? ~b : (b | 0x80000000u);
}

__device__ const int d_aoff[5]   = {0, 196608, 245760, 258048, 261120};
__device__ const int d_M[5]      = {196608, 49152, 12288, 3072, 768};
__device__ const int d_K[5]      = {1000, 1000, 1000, 1000, 768};
__device__ const int d_catoff[5] = {0, 1000, 2000, 3000, 4000};

// -------- weight transpose: [o][c][3x3] -> [c][k][ol][j]  (o = j*64+ol) --------
__global__ void kwt(const float* __restrict__ w_conv, float* __restrict__ wt){
  int i = blockIdx.x*256 + threadIdx.x;
  if (i < 256*256*9){
    int j = i & 3; int t = i >> 2;
    int ol = t & 63; int t2 = t >> 6;
    int k = t2 % 9; int c = t2 / 9;
    int o = j*64 + ol;
    wt[i] = w_conv[(o*256 + c)*9 + k];
  }
}

// -------- fused conv3x3 + relu + heads + box decode --------
// thread (ol=tid>>2, pg=tid&3) computes channels {ol+64j, j=0..3} x pixels [pg*PXT, pg*PXT+PXT)
template<int TP>
__global__ __launch_bounds__(256, 3) void kconv(
    const float* __restrict__ f, const float* __restrict__ wtt, const float* __restrict__ b_conv,
    const float* __restrict__ w_obj, const float* __restrict__ b_obj,
    const float* __restrict__ w_delta, const float* __restrict__ b_delta,
    float* __restrict__ scores_ws, float* __restrict__ boxes_ws,
    int H, int W, int aoff, float fstride,
    float aw0, float aw1, float aw2, float ah0, float ah1, float ah2)
{
  constexpr int PXT = TP/4;
  constexpr int XSS = TP + 8;   // row stride (16B aligned), halo 2 + pad
  constexpr int TLS = TP + 1;   // odd -> conflict-free column reads
  __shared__ float xs[2][3*XSS];
  __shared__ float t_lds[64*TLS];
  __shared__ float hb[16*TP];

  const int tid = threadIdx.x;
  const int w0 = blockIdx.x * TP;
  const int h  = blockIdx.y;
  const int n  = blockIdx.z;
  const int ol = tid >> 2;
  const int pg = tid & 3;
  const int px0 = pg * PXT;

  float acc[4][PXT];
  #pragma unroll
  for (int j = 0; j < 4; j++)
    #pragma unroll
    for (int p = 0; p < PXT; p++) acc[j][p] = 0.f;

  const int NSTG = 3*(TP+2);
  int sdy = tid / (TP+2), sdx = tid % (TP+2);
  int sy = h - 1 + sdy, sx = w0 - 1 + sdx;
  bool sthr = (tid < NSTG);
  bool sok = sthr && sy >= 0 && sy < H && sx >= 0 && sx < W;
  const long long fbase = (long long)n*256*H*W;
  long long soff_i = (long long)sy*W + sx;

  // stage c=0
  if (sthr) xs[0][sdy*XSS + sdx] = sok ? f[fbase + soff_i] : 0.f;
  __syncthreads();

  const float4* wt4 = (const float4*)wtt;

  for (int c = 0; c < 256; c++){
    float gx = 0.f;
    if (c < 255 && sthr) gx = sok ? f[fbase + (long long)(c+1)*H*W + soff_i] : 0.f;

    float4 wq[9];
    #pragma unroll
    for (int k = 0; k < 9; k++) wq[k] = wt4[(c*9 + k)*64 + ol];

    const float* xb = &xs[c & 1][0];
    #pragma unroll
    for (int dy = 0; dy < 3; dy++){
      const float* row = xb + dy*XSS + px0;
      float xr[PXT+2];
      #pragma unroll
      for (int t = 0; t < PXT; t += 4){
        float4 q = *(const float4*)(row + t);
        xr[t]=q.x; xr[t+1]=q.y; xr[t+2]=q.z; xr[t+3]=q.w;
      }
      xr[PXT]   = row[PXT];
      xr[PXT+1] = row[PXT+1];
      float4 qa = wq[3*dy], qb = wq[3*dy+1], qc = wq[3*dy+2];
      float wa[4] = {qa.x, qa.y, qa.z, qa.w};
      float wb[4] = {qb.x, qb.y, qb.z, qb.w};
      float wc[4] = {qc.x, qc.y, qc.z, qc.w};
      #pragma unroll
      for (int j = 0; j < 4; j++)
        #pragma unroll
        for (int pp = 0; pp < PXT; pp++)
          acc[j][pp] += wa[j]*xr[pp] + wb[j]*xr[pp+1] + wc[j]*xr[pp+2];
    }

    if (c < 255 && sthr) xs[(c+1)&1][sdy*XSS + sdx] = gx;
    __syncthreads();
  }

  // bias + relu
  #pragma unroll
  for (int j = 0; j < 4; j++){
    float bc = b_conv[j*64 + ol];
    #pragma unroll
    for (int p = 0; p < PXT; p++){ float v = acc[j][p] + bc; acc[j][p] = v > 0.f ? v : 0.f; }
  }

  // heads: 15 dot products of length 256 per pixel, via 4 quarter-passes of t_lds
  constexpr int G = 256 / TP;
  constexpr int HPT = (15 + G - 1) / G;
  const int p = tid & (TP-1);
  const int g = tid / TP;
  const float* wj[HPT];
  int jidx[HPT];
  float hacc[HPT];
  #pragma unroll
  for (int q = 0; q < HPT; q++){
    int j = g*HPT + q;
    jidx[q] = j;
    hacc[q] = 0.f;
    wj[q] = (j < 3) ? (w_obj + j*256) : ((j < 15) ? (w_delta + (j-3)*256) : w_obj);
  }
  for (int quarter = 0; quarter < 4; quarter++){
    __syncthreads();
    #pragma unroll
    for (int px = 0; px < PXT; px++) t_lds[ol*TLS + px0 + px] = acc[quarter][px];
    __syncthreads();
    for (int oo = 0; oo < 64; oo++){
      float tv = t_lds[oo*TLS + p];
      int ob = quarter*64 + oo;
      #pragma unroll
      for (int q = 0; q < HPT; q++) hacc[q] += wj[q][ob] * tv;
    }
  }
  #pragma unroll
  for (int q = 0; q < HPT; q++){
    int j = jidx[q];
    if (j < 15){
      float bias = (j < 3) ? b_obj[j] : b_delta[j-3];
      hb[j*TP + p] = hacc[q] + bias;
    }
  }
  __syncthreads();

  // box decode + clip + write
  if (tid < 3*TP){
    int a = tid % 3, pp = tid / 3;
    float score = hb[a*TP + pp];
    float dx  = hb[(3 + a*4 + 0)*TP + pp];
    float dyv = hb[(3 + a*4 + 1)*TP + pp];
    float dw  = hb[(3 + a*4 + 2)*TP + pp];
    float dh  = hb[(3 + a*4 + 3)*TP + pp];
    float aw = (a==0)?aw0:((a==1)?aw1:aw2);
    float ah = (a==0)?ah0:((a==1)?ah1:ah2);
    float gx = (float)(w0 + pp) * fstride;
    float gy = (float)h * fstride;
    float pcx = dx*aw + gx;
    float pcy = dyv*ah + gy;
    float pw = expf(fminf(dw, SCALE_CLAMP_F))*aw;
    float ph = expf(fminf(dh, SCALE_CLAMP_F))*ah;
    float x1 = pcx - 0.5f*pw, y1 = pcy - 0.5f*ph;
    float x2 = pcx + 0.5f*pw, y2 = pcy + 0.5f*ph;
    x1 = fminf(fmaxf(x1, 0.f), IMG_F); y1 = fminf(fmaxf(y1, 0.f), IMG_F);
    x2 = fminf(fmaxf(x2, 0.f), IMG_F); y2 = fminf(fmaxf(y2, 0.f), IMG_F);
    long long ai = (long long)n*SC_TOT + aoff + (long long)(h*W + w0 + pp)*3 + a;
    scores_ws[ai] = score;
    ((float4*)boxes_ws)[ai] = make_float4(x1, y1, x2, y2);
  }
}

// -------------------- zero scratch --------------------
__global__ void kzero(unsigned* ghist, int* cnts, int* meta){
  int i = blockIdx.x*256 + threadIdx.x;
  if (i < 4*10*256) ghist[i] = 0u;
  if (i < 32){ cnts[i] = 0; meta[i] = 0; }
}

// -------------------- radix-select histogram pass --------------------
__global__ __launch_bounds__(256) void khist(const float* __restrict__ scores_ws,
    unsigned* __restrict__ ghist, const int* __restrict__ meta, int pass)
{
  int seg = blockIdx.y; int img = seg/5, lvl = seg%5;
  int M = d_M[lvl];
  const float* sc = scores_ws + (long long)img*SC_TOT + d_aoff[lvl];
  __shared__ unsigned h[256];
  if (threadIdx.x < 256) h[threadIdx.x] = 0u;
  __syncthreads();
  int shift = 24 - 8*pass;
  unsigned prefix = (pass > 0) ? ((const unsigned*)meta)[seg*2] : 0u;
  unsigned pmask  = (pass > 0) ? (0xFFFFFFFFu << (shift+8)) : 0u;
  int chunk = (M + (int)gridDim.x - 1) / (int)gridDim.x;
  int lo = blockIdx.x*chunk, hiI = min(lo+chunk, M);
  for (int i = lo + threadIdx.x; i < hiI; i += 256){
    unsigned u = ufloat(sc[i]);
    if (((u ^ prefix) & pmask) == 0u) atomicAdd(&h[(u>>shift)&255u], 1u);
  }
  __syncthreads();
  unsigned* gh = ghist + (pass*10 + seg)*256;
  if (threadIdx.x < 256 && h[threadIdx.x]) atomicAdd(&gh[threadIdx.x], h[threadIdx.x]);
}

__global__ void kscan(const unsigned* __restrict__ ghist, int* meta, int pass){
  int seg = threadIdx.x;
  if (seg < 10){
    int lvl = seg % 5; int k = d_K[lvl];
    unsigned prefix = 0u; int rem = k;
    if (pass > 0){ prefix = ((unsigned*)meta)[seg*2]; rem = meta[seg*2+1]; }
    const unsigned* h = ghist + (pass*10+seg)*256;
    int shift = 24 - 8*pass;
    int r = rem; int b = 0;
    for (int x = 255; x >= 0; x--){
      int c = (int)h[x];
      if (c >= r){ b = x; break; }
      r -= c;
    }
    ((unsigned*)meta)[seg*2] = prefix | ((unsigned)b << shift);
    meta[seg*2+1] = r;
  }
}

// -------------------- selection (threshold from radix-select) --------------------
__global__ __launch_bounds__(256) void kselect(const float* __restrict__ scores_ws,
    const int* __restrict__ meta, unsigned long long* __restrict__ selg,
    unsigned* __restrict__ tieg, int* __restrict__ cnts)
{
  int seg = blockIdx.y; int img = seg/5, lvl = seg%5;
  int M = d_M[lvl];
  const float* sc = scores_ws + (long long)img*SC_TOT + d_aoff[lvl];
  unsigned ut = ((const unsigned*)meta)[seg*2];
  int chunk = (M + (int)gridDim.x - 1) / (int)gridDim.x;
  int lo = blockIdx.x*chunk, hiI = min(lo+chunk, M);
  for (int i = lo + threadIdx.x; i < hiI; i += 256){
    unsigned u = ufloat(sc[i]);
    if (u > ut){
      int pp = atomicAdd(&cnts[seg*2], 1);
      if (pp < 1024) selg[seg*1024 + pp] = ((unsigned long long)u << 32) | (unsigned)(~(unsigned)i);
    } else if (u == ut){
      int pp = atomicAdd(&cnts[seg*2+1], 1);
      if (pp < 1024) tieg[seg*1024 + pp] = (unsigned)i;
    }
  }
}

// -------------------- per-(img,lvl) sort of selected k --------------------
__device__ __forceinline__ void bitonic_u32_asc(unsigned* a, int tid){
  for (int k2 = 2; k2 <= 1024; k2 <<= 1)
    for (int j = k2>>1; j > 0; j >>= 1){
      int ixj = tid ^ j;
      if (ixj > tid){
        unsigned A = a[tid], B = a[ixj];
        bool up = ((tid & k2) == 0);
        if (up ? (A > B) : (A < B)){ a[tid] = B; a[ixj] = A; }
      }
      __syncthreads();
    }
}
__device__ __forceinline__ void bitonic_u64_desc(unsigned long long* a, int tid){
  for (int k2 = 2; k2 <= 1024; k2 <<= 1)
    for (int j = k2>>1; j > 0; j >>= 1){
      int ixj = tid ^ j;
      if (ixj > tid){
        unsigned long long A = a[tid], B = a[ixj];
        bool up = ((tid & k2) == 0);
        if (up ? (A < B) : (A > B)){ a[tid] = B; a[ixj] = A; }
      }
      __syncthreads();
    }
}

__global__ __launch_bounds__(1024) void ksort(const float* __restrict__ scores_ws,
    const float* __restrict__ boxes_ws, const unsigned long long* __restrict__ selg,
    const unsigned* __restrict__ tieg, const int* __restrict__ cnts, const int* __restrict__ meta,
    float* __restrict__ cat_scores, unsigned* __restrict__ cat_u, float* __restrict__ cat_boxes)
{
  int seg = blockIdx.x; int img = seg/5, lvl = seg%5;
  int k = d_K[lvl];
  unsigned ut = ((const unsigned*)meta)[seg*2];
  int cg = cnts[seg*2];
  int ct = min(cnts[seg*2+1], 1024);
  __shared__ unsigned long long sb[1024];
  __shared__ unsigned tb[1024];
  int tid = threadIdx.x;
  tb[tid] = (tid < ct) ? tieg[seg*1024 + tid] : 0xFFFFFFFFu;
  __syncthreads();
  bitonic_u32_asc(tb, tid);
  unsigned long long v = 0ull;
  if (tid < cg && tid < 1024) v = selg[seg*1024 + tid];
  else if (tid >= cg && tid < k) v = ((unsigned long long)ut << 32) | (unsigned)(~tb[tid - cg]);
  sb[tid] = v;
  __syncthreads();
  bitonic_u64_desc(sb, tid);
  if (tid < k){
    unsigned long long e = sb[tid];
    unsigned idx = ~(unsigned)e;
    unsigned u = (unsigned)(e >> 32);
    int pos = d_catoff[lvl] + tid;
    long long src = (long long)img*SC_TOT + d_aoff[lvl] + idx;
    cat_scores[img*T_CAT + pos] = scores_ws[src];
    cat_u[img*T_CAT + pos] = u;
    ((float4*)cat_boxes)[img*T_CAT + pos] = ((const float4*)boxes_ws)[src];
  }
}

// -------------------- stable global merge-rank --------------------
__device__ __forceinline__ int cnt_gt_desc(const unsigned* a, int len, unsigned u){
  int lo=0, hi=len;
  while (lo<hi){ int m=(lo+hi)>>1; if (a[m] > u) lo=m+1; else hi=m; }
  return lo;
}
__device__ __forceinline__ int cnt_ge_desc(const unsigned* a, int len, unsigned u){
  int lo=0, hi=len;
  while (lo<hi){ int m=(lo+hi)>>1; if (a[m] >= u) lo=m+1; else hi=m; }
  return lo;
}

__global__ void krank(const float* __restrict__ cat_scores, const unsigned* __restrict__ cat_u,
    const float* __restrict__ cat_boxes, float* __restrict__ sscore, float* __restrict__ sbox,
    float* __restrict__ soff, int* __restrict__ svalid)
{
  int img = blockIdx.y;
  int pos = blockIdx.x*256 + threadIdx.x;
  if (pos >= T_CAT) return;
  const unsigned* cu = cat_u + img*T_CAT;
  int lvl = pos / 1000; if (lvl > 4) lvl = 4;
  unsigned u = cu[pos];
  int rank = pos - d_catoff[lvl];
  #pragma unroll
  for (int l2 = 0; l2 < 5; l2++){
    if (l2 == lvl) continue;
    const unsigned* segp = cu + d_catoff[l2];
    int len = d_K[l2];
    rank += (l2 < lvl) ? cnt_ge_desc(segp, len, u) : cnt_gt_desc(segp, len, u);
  }
  float s = cat_scores[img*T_CAT + pos];
  float4 b = ((const float4*)cat_boxes)[img*T_CAT + pos];
  sscore[img*T_CAT + rank] = s;
  ((float4*)sbox)[img*T_CAT + rank] = b;
  float of = (float)lvl * (IMG_F + 1.0f);
  ((float4*)soff)[img*T_CAT + rank] = make_float4(b.x+of, b.y+of, b.z+of, b.w+of);
  svalid[img*T_CAT + rank] = ((b.z - b.x > 0.0f) && (b.w - b.y > 0.0f)) ? 1 : 0;
}

// -------------------- IoU suppression bitmask (idx>i baked in) --------------------
__global__ __launch_bounds__(256) void kiou(const float* __restrict__ soff,
    unsigned long long* __restrict__ mask)
{
  int rowt = blockIdx.x, img = blockIdx.y;
  int wv = threadIdx.x >> 6, lane = threadIdx.x & 63;
  const float4* sb4 = (const float4*)soff + (long long)img*T_CAT;
  for (int rr = 0; rr < 16; rr++){
    int row = rowt*64 + wv*16 + rr;
    if (row >= T_CAT) break;
    float4 rb = sb4[row];
    float rarea = (rb.z - rb.x)*(rb.w - rb.y);
    for (int w = 0; w < NWORDS; w++){
      int col = w*64 + lane;
      bool pred = false;
      if (col < T_CAT && col > row){
        float4 cb = sb4[col];
        float carea = (cb.z - cb.x)*(cb.w - cb.y);
        float ltx = fmaxf(rb.x, cb.x), lty = fmaxf(rb.y, cb.y);
        float rbx = fminf(rb.z, cb.z), rby = fminf(rb.w, cb.w);
        float wx = fmaxf(rbx - ltx, 0.f), wy = fmaxf(rby - lty, 0.f);
        float inter = wx*wy;
        float uni = rarea + carea - inter;
        float iou = (uni > 0.f) ? (inter/uni) : 0.f;
        pred = iou > 0.7f;
      }
      unsigned long long b = __ballot(pred);
      if (lane == 0) mask[((long long)img*T_CAT + row)*NWORDS + w] = b;
    }
  }
}

// -------------------- greedy scan + finalize --------------------
__global__ __launch_bounds__(256) void knms(const unsigned long long* __restrict__ mask,
    const int* __restrict__ svalid, const float* __restrict__ sscore,
    const float* __restrict__ sbox, float* __restrict__ out)
{
  int img = blockIdx.x; int tid = threadIdx.x;
  __shared__ unsigned long long keep[NWORDS];
  __shared__ unsigned long long curs;
  __shared__ unsigned long long keepv[NWORDS];
  __shared__ int pk[NWORDS], pu[NWORDS];
  __shared__ int Ktot;
  for (int i = tid; i < NWORDS; i += 256) keep[i] = ~0ull;
  __syncthreads();
  const unsigned long long* mk = mask + (long long)img*T_CAT*NWORDS;
  for (int w0 = 0; w0 < NWORDS; w0++){
    if (tid < 64){
      int row = w0*64 + tid;
      unsigned long long m = (row < T_CAT) ? mk[(long long)row*NWORDS + w0] : 0ull;
      unsigned long long cur = keep[w0];
      for (int l = 0; l < 64; l++){
        unsigned long long ml = __shfl(m, l);
        if ((cur >> l) & 1ull) cur &= ~ml;
      }
      if (tid == 0){ keep[w0] = cur; curs = cur; }
    }
    __syncthreads();
    unsigned long long cur = curs;
    for (int w = w0 + 1 + tid; w < NWORDS; w += 256){
      unsigned long long kw = keep[w];
      for (int l = 0; l < 64; l++){
        if ((cur >> l) & 1ull)
          kw &= ~mk[(long long)(w0*64 + l)*NWORDS + w];
      }
      keep[w] = kw;
    }
    __syncthreads();
  }
  for (int w = tid; w < NWORDS; w += 256){
    unsigned long long pres = (w < NWORDS-1) ? ~0ull : ((1ull << (T_CAT - 64*(NWORDS-1))) - 1ull);
    unsigned long long vb = 0ull;
    int base = w*64;
    for (int l = 0; l < 64; l++){
      int i = base + l;
      if (i < T_CAT && svalid[img*T_CAT + i]) vb |= (1ull << l);
    }
    keepv[w] = keep[w] & pres & vb;
  }
  __syncthreads();
  if (tid == 0){
    int s = 0;
    for (int w = 0; w < NWORDS; w++){ pk[w] = s; s += __popcll(keepv[w]); }
    Ktot = s;
    int su = 0;
    for (int w = 0; w < NWORDS; w++){
      unsigned long long pres = (w < NWORDS-1) ? ~0ull : ((1ull<<32) - 1ull);
      pu[w] = su; su += __popcll(pres & ~keepv[w]);
    }
  }
  __syncthreads();
  int K = Ktot;
  for (int i = tid; i < T_CAT; i += 256){
    int w = i >> 6, l = i & 63;
    unsigned long long kvw = keepv[w];
    bool kept = (kvw >> l) & 1ull;
    unsigned long long low = (l == 0) ? 0ull : ((1ull << l) - 1ull);
    int slot;
    if (kept) slot = pk[w] + __popcll(kvw & low);
    else {
      unsigned long long pres = (w < NWORDS-1) ? ~0ull : ((1ull<<32) - 1ull);
      slot = K + pu[w] + __popcll(pres & ~kvw & low);
    }
    if (slot < POST){
      float4 b = ((const float4*)sbox)[img*T_CAT + i];
      ((float4*)out)[img*POST + slot] = b;
      out[2*POST*4 + img*POST + slot] = kept ? sscore[img*T_CAT + i] : -__builtin_huge_valf();
    }
  }
}

// -------------------- host --------------------
extern "C" void kernel_launch(void* const* d_in, const int* in_sizes, int n_in,
                              void* d_out, int out_size, void* d_ws, size_t ws_size,
                              hipStream_t stream)
{
  const float* feats[5];
  for (int i = 0; i < 5; i++) feats[i] = (const float*)d_in[i];
  const float* w_conv  = (const float*)d_in[5];
  const float* b_conv  = (const float*)d_in[6];
  const float* w_obj   = (const float*)d_in[7];
  const float* b_obj   = (const float*)d_in[8];
  const float* w_delta = (const float*)d_in[9];
  const float* b_delta = (const float*)d_in[10];

  char* ws = (char*)d_ws;
  size_t off = 0;
  auto alloc = [&](size_t bytes)->char*{ char* r = ws + off; off += (bytes + 255) & ~(size_t)255; return r; };
  float*    wt         = (float*)   alloc(256*256*9*4);
  float*    scores_ws  = (float*)   alloc((size_t)2*SC_TOT*4);
  float*    boxes_ws   = (float*)   alloc((size_t)2*SC_TOT*16);
  float*    cat_scores = (float*)   alloc((size_t)2*T_CAT*4);
  unsigned* cat_u      = (unsigned*)alloc((size_t)2*T_CAT*4);
  float*    cat_boxes  = (float*)   alloc((size_t)2*T_CAT*16);
  float*    sscore     = (float*)   alloc((size_t)2*T_CAT*4);
  float*    sbox       = (float*)   alloc((size_t)2*T_CAT*16);
  float*    soff_b     = (float*)   alloc((size_t)2*T_CAT*16);
  int*      svalid     = (int*)     alloc((size_t)2*T_CAT*4);
  unsigned long long* mask = (unsigned long long*)alloc((size_t)2*T_CAT*NWORDS*8);
  unsigned* ghist      = (unsigned*)alloc(4*10*256*4);
  int*      meta       = (int*)     alloc(256);
  unsigned long long* selg = (unsigned long long*)alloc(10*1024*8);
  unsigned* tieg       = (unsigned*)alloc(10*1024*4);
  int*      cnts       = (int*)     alloc(256);
  (void)ws_size; (void)in_sizes; (void)n_in; (void)out_size;

  kwt<<<(256*256*9 + 255)/256, 256, 0, stream>>>(w_conv, wt);
  kzero<<<40, 256, 0, stream>>>(ghist, cnts, meta);

  struct Lv { int H, W, TP, aoff; float size, stride; };
  static const Lv LV[5] = {
    {256,256,64, 0,      32.f,  4.f},
    {128,128,32, 196608, 64.f,  8.f},
    {64, 64, 16, 245760, 128.f, 16.f},
    {32, 32, 16, 258048, 256.f, 32.f},
    {16, 16, 16, 261120, 512.f, 64.f},
  };
  const float ratios[3] = {0.5f, 1.0f, 2.0f};
  for (int l = 0; l < 5; l++){
    float area = LV[l].size * LV[l].size;
    float aw[3], ah[3];
    for (int a = 0; a < 3; a++){ aw[a] = sqrtf(area / ratios[a]); ah[a] = aw[a] * ratios[a]; }
    dim3 grid(LV[l].W / LV[l].TP, LV[l].H, 2);
    if (LV[l].TP == 64)
      kconv<64><<<grid, 256, 0, stream>>>(feats[l], wt, b_conv, w_obj, b_obj, w_delta, b_delta,
        scores_ws, boxes_ws, LV[l].H, LV[l].W, LV[l].aoff, LV[l].stride,
        aw[0],aw[1],aw[2], ah[0],ah[1],ah[2]);
    else if (LV[l].TP == 32)
      kconv<32><<<grid, 256, 0, stream>>>(feats[l], wt, b_conv, w_obj, b_obj, w_delta, b_delta,
        scores_ws, boxes_ws, LV[l].H, LV[l].W, LV[l].aoff, LV[l].stride,
        aw[0],aw[1],aw[2], ah[0],ah[1],ah[2]);
    else
      kconv<16><<<grid, 256, 0, stream>>>(feats[l], wt, b_conv, w_obj, b_obj, w_delta, b_delta,
        scores_ws, boxes_ws, LV[l].H, LV[l].W, LV[l].aoff, LV[l].stride,
        aw[0],aw[1],aw[2], ah[0],ah[1],ah[2]);
  }

  for (int pass = 0; pass < 4; pass++){
    khist<<<dim3(32,10), 256, 0, stream>>>(scores_ws, ghist, meta, pass);
    kscan<<<1, 64, 0, stream>>>(ghist, meta, pass);
  }
  kselect<<<dim3(32,10), 256, 0, stream>>>(scores_ws, meta, selg, tieg, cnts);
  ksort<<<10, 1024, 0, stream>>>(scores_ws, boxes_ws, selg, tieg, cnts, meta,
                                 cat_scores, cat_u, cat_boxes);
  krank<<<dim3((T_CAT+255)/256, 2), 256, 0, stream>>>(cat_scores, cat_u, cat_boxes,
                                                      sscore, sbox, soff_b, svalid);
  kiou<<<dim3(NWORDS, 2), 256, 0, stream>>>(soff_b, mask);
  knms<<<2, 256, 0, stream>>>(mask, svalid, sscore, sbox, (float*)d_out);
}

// Round 3
// 3027.492 us; speedup vs baseline: 2.7290x; 2.1417x over previous
//
#include <hip/hip_runtime.h>
#include <hip/hip_fp16.h>
#include <math.h>

#define SC_TOT   261888
#define T_CAT    4768
#define NWORDS   75
#define POST     1000
#define IMG_F    1024.0f
#define SCALE_CLAMP_F 4.135166556742356f
#define TOTG     5715200

typedef _Float16 half8 __attribute__((ext_vector_type(8)));
typedef short   short8 __attribute__((ext_vector_type(8)));
typedef float  floatx4 __attribute__((ext_vector_type(4)));

__device__ __forceinline__ unsigned ufloat(float f){
  unsigned b = __float_as_uint(f);
  return (b & 0x80000000u) ? ~b : (b | 0x80000000u);
}
__device__ __forceinline__ short f2bf_rne(float f){
  unsigned u = __float_as_uint(f);
  u += 0x7FFFu + ((u>>16)&1u);
  return (short)(u>>16);
}
// f16x8 -> bf16x8 (truncating; feeds 2^-12-scale correction terms, bias ~2^-20 total)
__device__ __forceinline__ short8 h2b(half8 h){
  union { half8 v; unsigned u[4]; } a; a.v = h;
  union { short8 v; unsigned u[4]; } r;
  #pragma unroll
  for (int i=0;i<4;i++){
    unsigned w = a.u[i];
    __half2 p = *reinterpret_cast<__half2*>(&w);
    float f0 = __low2float(p), f1 = __high2float(p);
    r.u[i] = __byte_perm(__float_as_uint(f0), __float_as_uint(f1), 0x7632);
  }
  return r.v;
}

__device__ const int d_aoff[5]   = {0, 196608, 245760, 258048, 261120};
__device__ const int d_M[5]      = {196608, 49152, 12288, 3072, 768};
__device__ const int d_K[5]      = {1000, 1000, 1000, 1000, 768};
__device__ const int d_catoff[5] = {0, 1000, 2000, 3000, 4000};

// =================== pre-pass: weight split into A-frag layout ===================
// idx = (((cc*9+s)*4+kq)*256+o)*8 + c8 ; c = cc*32+kq*8+c8 ; k = s
__global__ void kwprep(const float* __restrict__ wsrc, _Float16* __restrict__ Whg, short* __restrict__ Wlg){
  int i = blockIdx.x*256 + threadIdx.x;
  if (i >= 256*256*9) return;
  int c8 = i&7, o = (i>>3)&255, kq = (i>>11)&3, rest = i>>13;
  int s = rest % 9, cc = rest / 9;
  int c = cc*32 + kq*8 + c8;
  float w = wsrc[(o*256 + c)*9 + s];
  _Float16 h = (_Float16)w;
  Whg[i] = h;
  Wlg[i] = f2bf_rne(w - (float)h);
}

// =================== pre-pass: X split into padded canvases ===================
struct XPar { int goff[6]; int HpWp[5]; int Wp[5]; int H[5]; int W[5]; };
__global__ void kxprep(const float* __restrict__ f0, const float* __restrict__ f1,
                       const float* __restrict__ f2, const float* __restrict__ f3,
                       const float* __restrict__ f4,
                       _Float16* __restrict__ Xh, short* __restrict__ Xl, XPar P)
{
  int gid = blockIdx.x*256 + threadIdx.x;
  if (gid >= TOTG) return;
  int lvl = 0;
  #pragma unroll
  for (int i=1;i<5;i++) if (gid >= P.goff[i]) lvl = i;
  int rem = gid - P.goff[lvl];
  int HpWp = P.HpWp[lvl], Wp = P.Wp[lvl], H = P.H[lvl], W = P.W[lvl];
  int n = rem / (HpWp*32); rem -= n*HpWp*32;
  int cg = rem / HpWp;     rem -= cg*HpWp;
  int y = rem / Wp;        int x = rem - y*Wp;
  const float* f = (lvl==0)?f0:(lvl==1)?f1:(lvl==2)?f2:(lvl==3)?f3:f4;
  bool inter = (x>=1) && (x<=W) && (y>=1) && (y<=H);
  long long base = inter ? (((long long)(n*256 + cg*8)*H + (y-1))*W + (x-1)) : 0;
  long long chs = (long long)H*W;
  half8 h; short8 l;
  #pragma unroll
  for (int c8=0;c8<8;c8++){
    float v = inter ? f[base + (long long)c8*chs] : 0.f;
    _Float16 hh = (_Float16)v;
    h[c8] = hh;
    l[c8] = f2bf_rne(v - (float)hh);
  }
  *(half8*)(Xh + (long long)gid*8) = h;
  *(short8*)(Xl + (long long)gid*8) = l;
}

// =================== unified MFMA conv + heads + decode ===================
struct CLP {
  int Hp, Wp, H, W, C, lcC, lxt, xtm1, R, TR, CP, TRCP, tpim1, ltpi, aoff, goff;
  float stride, aw0, aw1, aw2, ah0, ah1, ah2;
};
struct CAll { CLP l[5]; int pref[6]; };

__global__ __launch_bounds__(256, 2) void kmf(
  const _Float16* __restrict__ Xh, const short* __restrict__ Xl,
  const _Float16* __restrict__ Whg, const short* __restrict__ Wlg,
  const float* __restrict__ b_conv, const float* __restrict__ w_obj, const float* __restrict__ b_obj,
  const float* __restrict__ w_delta, const float* __restrict__ b_delta,
  float* __restrict__ scores_ws, float* __restrict__ boxes_ws, CAll A)
{
  __shared__ float whead_s[3840];
  __shared__ float bconv_s[256];
  __shared__ __align__(16) char uni[33792];
  _Float16* XT_h = (_Float16*)uni;           // 1056 groups * 16B
  short*    XT_l = (short*)(uni + 16896);
  float*    hb2  = (float*)uni;              // reused after conv: 4*15*128 floats

  const int tid  = threadIdx.x;
  const int wv   = tid >> 6;
  const int lane = tid & 63;
  const int l15  = lane & 15;
  const int kq   = lane >> 4;

  int lvl = 0;
  #pragma unroll
  for (int i=1;i<5;i++) if ((int)blockIdx.x >= A.pref[i]) lvl = i;
  const CLP P = A.l[lvl];
  int bl = blockIdx.x - A.pref[lvl];
  int n  = bl >> P.ltpi;
  int t  = bl & P.tpim1;
  int y0 = (t >> P.lxt) * P.R;
  int x0 = (t & P.xtm1) * P.C;

  for (int i = tid; i < 3840; i += 256) whead_s[i] = (i < 768) ? w_obj[i] : w_delta[i-768];
  bconv_s[tid] = b_conv[tid];

  floatx4 acc[4][8];
  #pragma unroll
  for (int mt=0;mt<4;mt++)
    #pragma unroll
    for (int nt=0;nt<8;nt++) acc[mt][nt] = (floatx4){0.f,0.f,0.f,0.f};

  const int TRCP = P.TRCP, CP = P.CP, TR = P.TR;
  const int U = 4*TRCP;

  for (int cc = 0; cc < 8; cc++){
    __syncthreads();
    for (int u = tid; u < U; u += 256){
      int kqs = u / TRCP;
      int rem = u - kqs*TRCP;
      int r   = rem / CP;
      int col = rem - r*CP;
      int src = P.goff + ((n*32 + cc*4 + kqs)*P.Hp + y0 + r)*P.Wp + x0 + col;
      *(uint4*)((char*)XT_h + u*16) = *(const uint4*)(Xh + (long long)src*8);
      *(uint4*)((char*)XT_l + u*16) = *(const uint4*)(Xl + (long long)src*8);
    }
    __syncthreads();

    for (int s = 0; s < 9; s++){
      int ky = s / 3, kx = s - ky*3;
      int wb = (((cc*9 + s)*4 + kq)*256) + 64*wv + l15;
      half8 ah[4]; short8 al[4], ahb[4];
      #pragma unroll
      for (int mt=0;mt<4;mt++){
        ah[mt]  = *(const half8*)(Whg + (long long)(wb + 16*mt)*8);
        al[mt]  = *(const short8*)(Wlg + (long long)(wb + 16*mt)*8);
        ahb[mt] = h2b(ah[mt]);
      }
      int rowbase = kq*TR + ky;
      #pragma unroll
      for (int nh=0;nh<2;nh++){
        half8 bh[4]; short8 bl[4], bhb[4];
        #pragma unroll
        for (int q=0;q<4;q++){
          int px  = (nh*4+q)*16 + l15;
          int r   = px >> P.lcC;
          int col = px & (P.C-1);
          int gi  = (rowbase + r)*CP + col + kx;
          bh[q]  = *(const half8*)((char*)XT_h + gi*16);
          bl[q]  = *(const short8*)((char*)XT_l + gi*16);
          bhb[q] = h2b(bh[q]);
        }
        #pragma unroll
        for (int mt=0;mt<4;mt++)
          #pragma unroll
          for (int q=0;q<4;q++){
            int nt = nh*4+q;
            acc[mt][nt] = __builtin_amdgcn_mfma_f32_16x16x32_f16 (ah[mt],  bh[q],  acc[mt][nt], 0,0,0);
            acc[mt][nt] = __builtin_amdgcn_mfma_f32_16x16x32_bf16(ahb[mt], bl[q],  acc[mt][nt], 0,0,0);
            acc[mt][nt] = __builtin_amdgcn_mfma_f32_16x16x32_bf16(al[mt],  bhb[q], acc[mt][nt], 0,0,0);
          }
      }
    }
  }

  // bias + relu (acc = t, rows o = 64wv+16mt+4kq+reg, cols px = nt*16+l15)
  #pragma unroll
  for (int mt=0;mt<4;mt++){
    floatx4 bc = *(const floatx4*)(bconv_s + 64*wv + 16*mt + 4*kq);
    #pragma unroll
    for (int nt=0;nt<8;nt++)
      #pragma unroll
      for (int e=0;e<4;e++){
        float v = acc[mt][nt][e] + bc[e];
        acc[mt][nt][e] = v > 0.f ? v : 0.f;
      }
  }
  __syncthreads();   // all XT reads done before hb2 overwrites uni

  // heads: per-wave partials over this wave's 64 o
  #pragma unroll
  for (int nh=0;nh<2;nh++){
    float sjq[15][4];
    #pragma unroll
    for (int j=0;j<15;j++)
      #pragma unroll
      for (int q=0;q<4;q++) sjq[j][q] = 0.f;
    for (int j=0;j<15;j++){
      #pragma unroll
      for (int mt=0;mt<4;mt++){
        floatx4 w4 = *(const floatx4*)(whead_s + j*256 + 64*wv + 16*mt + 4*kq);
        #pragma unroll
        for (int q=0;q<4;q++){
          floatx4 t4 = acc[mt][nh*4+q];
          sjq[j][q] += w4[0]*t4[0] + w4[1]*t4[1] + w4[2]*t4[2] + w4[3]*t4[3];
        }
      }
    }
    #pragma unroll
    for (int j=0;j<15;j++)
      #pragma unroll
      for (int q=0;q<4;q++){
        float v = sjq[j][q];
        v += __shfl_xor(v, 16);
        v += __shfl_xor(v, 32);
        if (kq == 0) hb2[(wv*15 + j)*128 + (nh*4+q)*16 + l15] = v;
      }
  }
  __syncthreads();

  // reduce over waves + decode + write
  for (int idx = tid; idx < 3*128; idx += 256){
    int a  = idx % 3;
    int px = idx / 3;
    int y = y0 + (px >> P.lcC);
    int x = x0 + (px & (P.C-1));
    float sc  = b_obj[a];
    float dx  = b_delta[a*4+0], dyv = b_delta[a*4+1];
    float dw  = b_delta[a*4+2], dh  = b_delta[a*4+3];
    #pragma unroll
    for (int w=0; w<4; w++){
      sc  += hb2[(w*15 + a)*128 + px];
      dx  += hb2[(w*15 + 3 + a*4+0)*128 + px];
      dyv += hb2[(w*15 + 3 + a*4+1)*128 + px];
      dw  += hb2[(w*15 + 3 + a*4+2)*128 + px];
      dh  += hb2[(w*15 + 3 + a*4+3)*128 + px];
    }
    float aw  = (a==0)?P.aw0:((a==1)?P.aw1:P.aw2);
    float ahh = (a==0)?P.ah0:((a==1)?P.ah1:P.ah2);
    float gx = (float)x * P.stride, gy = (float)y * P.stride;
    float pcx = dx*aw + gx, pcy = dyv*ahh + gy;
    float pw = expf(fminf(dw, SCALE_CLAMP_F))*aw;
    float ph = expf(fminf(dh, SCALE_CLAMP_F))*ahh;
    float x1 = fminf(fmaxf(pcx - 0.5f*pw, 0.f), IMG_F);
    float y1 = fminf(fmaxf(pcy - 0.5f*ph, 0.f), IMG_F);
    float x2 = fminf(fmaxf(pcx + 0.5f*pw, 0.f), IMG_F);
    float y2 = fminf(fmaxf(pcy + 0.5f*ph, 0.f), IMG_F);
    long long ai = (long long)n*SC_TOT + P.aoff + (long long)(y*P.W + x)*3 + a;
    scores_ws[ai] = sc;
    ((float4*)boxes_ws)[ai] = make_float4(x1,y1,x2,y2);
  }
}

// =================== fallback fp32 conv (round-2 path) ===================
__global__ void kwt(const float* __restrict__ w_conv, float* __restrict__ wt){
  int i = blockIdx.x*256 + threadIdx.x;
  if (i < 256*256*9){
    int j = i & 3; int t = i >> 2;
    int ol = t & 63; int t2 = t >> 6;
    int k = t2 % 9; int c = t2 / 9;
    int o = j*64 + ol;
    wt[i] = w_conv[(o*256 + c)*9 + k];
  }
}

template<int TP>
__global__ __launch_bounds__(256, 3) void kconv(
    const float* __restrict__ f, const float* __restrict__ wtt, const float* __restrict__ b_conv,
    const float* __restrict__ w_obj, const float* __restrict__ b_obj,
    const float* __restrict__ w_delta, const float* __restrict__ b_delta,
    float* __restrict__ scores_ws, float* __restrict__ boxes_ws,
    int H, int W, int aoff, float fstride,
    float aw0, float aw1, float aw2, float ah0, float ah1, float ah2)
{
  constexpr int PXT = TP/4;
  constexpr int XSS = TP + 8;
  constexpr int TLS = TP + 1;
  __shared__ float xs[2][3*XSS];
  __shared__ float t_lds[64*TLS];
  __shared__ float hb[16*TP];

  const int tid = threadIdx.x;
  const int w0 = blockIdx.x * TP;
  const int h  = blockIdx.y;
  const int n  = blockIdx.z;
  const int ol = tid >> 2;
  const int pg = tid & 3;
  const int px0 = pg * PXT;

  float acc[4][PXT];
  #pragma unroll
  for (int j = 0; j < 4; j++)
    #pragma unroll
    for (int p = 0; p < PXT; p++) acc[j][p] = 0.f;

  const int NSTG = 3*(TP+2);
  int sdy = tid / (TP+2), sdx = tid % (TP+2);
  int sy = h - 1 + sdy, sx = w0 - 1 + sdx;
  bool sthr = (tid < NSTG);
  bool sok = sthr && sy >= 0 && sy < H && sx >= 0 && sx < W;
  const long long fbase = (long long)n*256*H*W;
  long long soff_i = (long long)sy*W + sx;

  if (sthr) xs[0][sdy*XSS + sdx] = sok ? f[fbase + soff_i] : 0.f;
  __syncthreads();

  const float4* wt4 = (const float4*)wtt;

  for (int c = 0; c < 256; c++){
    float gx = 0.f;
    if (c < 255 && sthr) gx = sok ? f[fbase + (long long)(c+1)*H*W + soff_i] : 0.f;

    float4 wq[9];
    #pragma unroll
    for (int k = 0; k < 9; k++) wq[k] = wt4[(c*9 + k)*64 + ol];

    const float* xb = &xs[c & 1][0];
    #pragma unroll
    for (int dy = 0; dy < 3; dy++){
      const float* row = xb + dy*XSS + px0;
      float xr[PXT+2];
      #pragma unroll
      for (int t = 0; t < PXT; t += 4){
        float4 q = *(const float4*)(row + t);
        xr[t]=q.x; xr[t+1]=q.y; xr[t+2]=q.z; xr[t+3]=q.w;
      }
      xr[PXT]   = row[PXT];
      xr[PXT+1] = row[PXT+1];
      float4 qa = wq[3*dy], qb = wq[3*dy+1], qc = wq[3*dy+2];
      float wa[4] = {qa.x, qa.y, qa.z, qa.w};
      float wb[4] = {qb.x, qb.y, qb.z, qb.w};
      float wc[4] = {qc.x, qc.y, qc.z, qc.w};
      #pragma unroll
      for (int j = 0; j < 4; j++)
        #pragma unroll
        for (int pp = 0; pp < PXT; pp++)
          acc[j][pp] += wa[j]*xr[pp] + wb[j]*xr[pp+1] + wc[j]*xr[pp+2];
    }

    if (c < 255 && sthr) xs[(c+1)&1][sdy*XSS + sdx] = gx;
    __syncthreads();
  }

  #pragma unroll
  for (int j = 0; j < 4; j++){
    float bc = b_conv[j*64 + ol];
    #pragma unroll
    for (int p = 0; p < PXT; p++){ float v = acc[j][p] + bc; acc[j][p] = v > 0.f ? v : 0.f; }
  }

  constexpr int G = 256 / TP;
  constexpr int HPT = (15 + G - 1) / G;
  const int p = tid & (TP-1);
  const int g = tid / TP;
  const float* wj[HPT];
  int jidx[HPT];
  float hacc[HPT];
  #pragma unroll
  for (int q = 0; q < HPT; q++){
    int j = g*HPT + q;
    jidx[q] = j;
    hacc[q] = 0.f;
    wj[q] = (j < 3) ? (w_obj + j*256) : ((j < 15) ? (w_delta + (j-3)*256) : w_obj);
  }
  for (int quarter = 0; quarter < 4; quarter++){
    __syncthreads();
    #pragma unroll
    for (int px = 0; px < PXT; px++) t_lds[ol*TLS + px0 + px] = acc[quarter][px];
    __syncthreads();
    for (int oo = 0; oo < 64; oo++){
      float tv = t_lds[oo*TLS + p];
      int ob = quarter*64 + oo;
      #pragma unroll
      for (int q = 0; q < HPT; q++) hacc[q] += wj[q][ob] * tv;
    }
  }
  #pragma unroll
  for (int q = 0; q < HPT; q++){
    int j = jidx[q];
    if (j < 15){
      float bias = (j < 3) ? b_obj[j] : b_delta[j-3];
      hb[j*TP + p] = hacc[q] + bias;
    }
  }
  __syncthreads();

  if (tid < 3*TP){
    int a = tid % 3, pp = tid / 3;
    float score = hb[a*TP + pp];
    float dx  = hb[(3 + a*4 + 0)*TP + pp];
    float dyv = hb[(3 + a*4 + 1)*TP + pp];
    float dw  = hb[(3 + a*4 + 2)*TP + pp];
    float dh  = hb[(3 + a*4 + 3)*TP + pp];
    float aw = (a==0)?aw0:((a==1)?aw1:aw2);
    float ah = (a==0)?ah0:((a==1)?ah1:ah2);
    float gx = (float)(w0 + pp) * fstride;
    float gy = (float)h * fstride;
    float pcx = dx*aw + gx;
    float pcy = dyv*ah + gy;
    float pw = expf(fminf(dw, SCALE_CLAMP_F))*aw;
    float ph = expf(fminf(dh, SCALE_CLAMP_F))*ah;
    float x1 = pcx - 0.5f*pw, y1 = pcy - 0.5f*ph;
    float x2 = pcx + 0.5f*pw, y2 = pcy + 0.5f*ph;
    x1 = fminf(fmaxf(x1, 0.f), IMG_F); y1 = fminf(fmaxf(y1, 0.f), IMG_F);
    x2 = fminf(fmaxf(x2, 0.f), IMG_F); y2 = fminf(fmaxf(y2, 0.f), IMG_F);
    long long ai = (long long)n*SC_TOT + aoff + (long long)(h*W + w0 + pp)*3 + a;
    scores_ws[ai] = score;
    ((float4*)boxes_ws)[ai] = make_float4(x1, y1, x2, y2);
  }
}

// -------------------- zero scratch --------------------
__global__ void kzero(unsigned* ghist, int* cnts, int* meta){
  int i = blockIdx.x*256 + threadIdx.x;
  if (i < 4*10*256) ghist[i] = 0u;
  if (i < 32){ cnts[i] = 0; meta[i] = 0; }
}

// -------------------- radix-select --------------------
__global__ __launch_bounds__(256) void khist(const float* __restrict__ scores_ws,
    unsigned* __restrict__ ghist, const int* __restrict__ meta, int pass)
{
  int seg = blockIdx.y; int img = seg/5, lvl = seg%5;
  int M = d_M[lvl];
  const float* sc = scores_ws + (long long)img*SC_TOT + d_aoff[lvl];
  __shared__ unsigned h[256];
  h[threadIdx.x] = 0u;
  __syncthreads();
  int shift = 24 - 8*pass;
  unsigned prefix = (pass > 0) ? ((const unsigned*)meta)[seg*2] : 0u;
  unsigned pmask  = (pass > 0) ? (0xFFFFFFFFu << (shift+8)) : 0u;
  int chunk = (M + (int)gridDim.x - 1) / (int)gridDim.x;
  int lo = blockIdx.x*chunk, hiI = min(lo+chunk, M);
  for (int i = lo + threadIdx.x; i < hiI; i += 256){
    unsigned u = ufloat(sc[i]);
    if (((u ^ prefix) & pmask) == 0u) atomicAdd(&h[(u>>shift)&255u], 1u);
  }
  __syncthreads();
  unsigned* gh = ghist + (pass*10 + seg)*256;
  if (h[threadIdx.x]) atomicAdd(&gh[threadIdx.x], h[threadIdx.x]);
}

__global__ void kscan(const unsigned* __restrict__ ghist, int* meta, int pass){
  int seg = threadIdx.x;
  if (seg < 10){
    int lvl = seg % 5; int k = d_K[lvl];
    unsigned prefix = 0u; int rem = k;
    if (pass > 0){ prefix = ((unsigned*)meta)[seg*2]; rem = meta[seg*2+1]; }
    const unsigned* h = ghist + (pass*10+seg)*256;
    int shift = 24 - 8*pass;
    int r = rem; int b = 0;
    for (int x = 255; x >= 0; x--){
      int c = (int)h[x];
      if (c >= r){ b = x; break; }
      r -= c;
    }
    ((unsigned*)meta)[seg*2] = prefix | ((unsigned)b << shift);
    meta[seg*2+1] = r;
  }
}

__global__ __launch_bounds__(256) void kselect(const float* __restrict__ scores_ws,
    const int* __restrict__ meta, unsigned long long* __restrict__ selg,
    unsigned* __restrict__ tieg, int* __restrict__ cnts)
{
  int seg = blockIdx.y; int img = seg/5, lvl = seg%5;
  int M = d_M[lvl];
  const float* sc = scores_ws + (long long)img*SC_TOT + d_aoff[lvl];
  unsigned ut = ((const unsigned*)meta)[seg*2];
  int chunk = (M + (int)gridDim.x - 1) / (int)gridDim.x;
  int lo = blockIdx.x*chunk, hiI = min(lo+chunk, M);
  for (int i = lo + threadIdx.x; i < hiI; i += 256){
    unsigned u = ufloat(sc[i]);
    if (u > ut){
      int pp = atomicAdd(&cnts[seg*2], 1);
      if (pp < 1024) selg[seg*1024 + pp] = ((unsigned long long)u << 32) | (unsigned)(~(unsigned)i);
    } else if (u == ut){
      int pp = atomicAdd(&cnts[seg*2+1], 1);
      if (pp < 1024) tieg[seg*1024 + pp] = (unsigned)i;
    }
  }
}

__device__ __forceinline__ void bitonic_u32_asc(unsigned* a, int tid){
  for (int k2 = 2; k2 <= 1024; k2 <<= 1)
    for (int j = k2>>1; j > 0; j >>= 1){
      int ixj = tid ^ j;
      if (ixj > tid){
        unsigned A = a[tid], B = a[ixj];
        bool up = ((tid & k2) == 0);
        if (up ? (A > B) : (A < B)){ a[tid] = B; a[ixj] = A; }
      }
      __syncthreads();
    }
}
__device__ __forceinline__ void bitonic_u64_desc(unsigned long long* a, int tid){
  for (int k2 = 2; k2 <= 1024; k2 <<= 1)
    for (int j = k2>>1; j > 0; j >>= 1){
      int ixj = tid ^ j;
      if (ixj > tid){
        unsigned long long A = a[tid], B = a[ixj];
        bool up = ((tid & k2) == 0);
        if (up ? (A < B) : (A > B)){ a[tid] = B; a[ixj] = A; }
      }
      __syncthreads();
    }
}

__global__ __launch_bounds__(1024) void ksort(const float* __restrict__ scores_ws,
    const float* __restrict__ boxes_ws, const unsigned long long* __restrict__ selg,
    const unsigned* __restrict__ tieg, const int* __restrict__ cnts, const int* __restrict__ meta,
    float* __restrict__ cat_scores, unsigned* __restrict__ cat_u, float* __restrict__ cat_boxes)
{
  int seg = blockIdx.x; int img = seg/5, lvl = seg%5;
  int k = d_K[lvl];
  unsigned ut = ((const unsigned*)meta)[seg*2];
  int cg = cnts[seg*2];
  int ct = min(cnts[seg*2+1], 1024);
  __shared__ unsigned long long sb[1024];
  __shared__ unsigned tb[1024];
  int tid = threadIdx.x;
  tb[tid] = (tid < ct) ? tieg[seg*1024 + tid] : 0xFFFFFFFFu;
  __syncthreads();
  bitonic_u32_asc(tb, tid);
  unsigned long long v = 0ull;
  if (tid < cg && tid < 1024) v = selg[seg*1024 + tid];
  else if (tid >= cg && tid < k) v = ((unsigned long long)ut << 32) | (unsigned)(~tb[tid - cg]);
  sb[tid] = v;
  __syncthreads();
  bitonic_u64_desc(sb, tid);
  if (tid < k){
    unsigned long long e = sb[tid];
    unsigned idx = ~(unsigned)e;
    unsigned u = (unsigned)(e >> 32);
    int pos = d_catoff[lvl] + tid;
    long long src = (long long)img*SC_TOT + d_aoff[lvl] + idx;
    cat_scores[img*T_CAT + pos] = scores_ws[src];
    cat_u[img*T_CAT + pos] = u;
    ((float4*)cat_boxes)[img*T_CAT + pos] = ((const float4*)boxes_ws)[src];
  }
}

__device__ __forceinline__ int cnt_gt_desc(const unsigned* a, int len, unsigned u){
  int lo=0, hi=len;
  while (lo<hi){ int m=(lo+hi)>>1; if (a[m] > u) lo=m+1; else hi=m; }
  return lo;
}
__device__ __forceinline__ int cnt_ge_desc(const unsigned* a, int len, unsigned u){
  int lo=0, hi=len;
  while (lo<hi){ int m=(lo+hi)>>1; if (a[m] >= u) lo=m+1; else hi=m; }
  return lo;
}

__global__ void krank(const float* __restrict__ cat_scores, const unsigned* __restrict__ cat_u,
    const float* __restrict__ cat_boxes, float* __restrict__ sscore, float* __restrict__ sbox,
    float* __restrict__ soff, int* __restrict__ svalid)
{
  int img = blockIdx.y;
  int pos = blockIdx.x*256 + threadIdx.x;
  if (pos >= T_CAT) return;
  const unsigned* cu = cat_u + img*T_CAT;
  int lvl = pos / 1000; if (lvl > 4) lvl = 4;
  unsigned u = cu[pos];
  int rank = pos - d_catoff[lvl];
  #pragma unroll
  for (int l2 = 0; l2 < 5; l2++){
    if (l2 == lvl) continue;
    const unsigned* segp = cu + d_catoff[l2];
    int len = d_K[l2];
    rank += (l2 < lvl) ? cnt_ge_desc(segp, len, u) : cnt_gt_desc(segp, len, u);
  }
  float s = cat_scores[img*T_CAT + pos];
  float4 b = ((const float4*)cat_boxes)[img*T_CAT + pos];
  sscore[img*T_CAT + rank] = s;
  ((float4*)sbox)[img*T_CAT + rank] = b;
  float of = (float)lvl * (IMG_F + 1.0f);
  ((float4*)soff)[img*T_CAT + rank] = make_float4(b.x+of, b.y+of, b.z+of, b.w+of);
  svalid[img*T_CAT + rank] = ((b.z - b.x > 0.0f) && (b.w - b.y > 0.0f)) ? 1 : 0;
}

__global__ __launch_bounds__(256) void kiou(const float* __restrict__ soff,
    unsigned long long* __restrict__ mask)
{
  int rowt = blockIdx.x, img = blockIdx.y;
  int wv = threadIdx.x >> 6, lane = threadIdx.x & 63;
  const float4* sb4 = (const float4*)soff + (long long)img*T_CAT;
  for (int rr = 0; rr < 16; rr++){
    int row = rowt*64 + wv*16 + rr;
    if (row >= T_CAT) break;
    float4 rb = sb4[row];
    float rarea = (rb.z - rb.x)*(rb.w - rb.y);
    for (int w = 0; w < NWORDS; w++){
      int col = w*64 + lane;
      bool pred = false;
      if (col < T_CAT && col > row){
        float4 cb = sb4[col];
        float carea = (cb.z - cb.x)*(cb.w - cb.y);
        float ltx = fmaxf(rb.x, cb.x), lty = fmaxf(rb.y, cb.y);
        float rbx = fminf(rb.z, cb.z), rby = fminf(rb.w, cb.w);
        float wx = fmaxf(rbx - ltx, 0.f), wy = fmaxf(rby - lty, 0.f);
        float inter = wx*wy;
        float uni = rarea + carea - inter;
        float iou = (uni > 0.f) ? (inter/uni) : 0.f;
        pred = iou > 0.7f;
      }
      unsigned long long b = __ballot(pred);
      if (lane == 0) mask[((long long)img*T_CAT + row)*NWORDS + w] = b;
    }
  }
}

__global__ __launch_bounds__(256) void knms(const unsigned long long* __restrict__ mask,
    const int* __restrict__ svalid, const float* __restrict__ sscore,
    const float* __restrict__ sbox, float* __restrict__ out)
{
  int img = blockIdx.x; int tid = threadIdx.x;
  __shared__ unsigned long long keep[NWORDS];
  __shared__ unsigned long long curs;
  __shared__ unsigned long long keepv[NWORDS];
  __shared__ int pk[NWORDS], pu[NWORDS];
  __shared__ int Ktot;
  for (int i = tid; i < NWORDS; i += 256) keep[i] = ~0ull;
  __syncthreads();
  const unsigned long long* mk = mask + (long long)img*T_CAT*NWORDS;
  for (int w0 = 0; w0 < NWORDS; w0++){
    if (tid < 64){
      int row = w0*64 + tid;
      unsigned long long m = (row < T_CAT) ? mk[(long long)row*NWORDS + w0] : 0ull;
      unsigned long long cur = keep[w0];
      for (int l = 0; l < 64; l++){
        unsigned long long ml = __shfl(m, l);
        if ((cur >> l) & 1ull) cur &= ~ml;
      }
      if (tid == 0){ keep[w0] = cur; curs = cur; }
    }
    __syncthreads();
    unsigned long long cur = curs;
    for (int w = w0 + 1 + tid; w < NWORDS; w += 256){
      unsigned long long kw = keep[w];
      for (int l = 0; l < 64; l++){
        if ((cur >> l) & 1ull)
          kw &= ~mk[(long long)(w0*64 + l)*NWORDS + w];
      }
      keep[w] = kw;
    }
    __syncthreads();
  }
  for (int w = tid; w < NWORDS; w += 256){
    unsigned long long pres = (w < NWORDS-1) ? ~0ull : ((1ull << (T_CAT - 64*(NWORDS-1))) - 1ull);
    unsigned long long vb = 0ull;
    int base = w*64;
    for (int l = 0; l < 64; l++){
      int i = base + l;
      if (i < T_CAT && svalid[img*T_CAT + i]) vb |= (1ull << l);
    }
    keepv[w] = keep[w] & pres & vb;
  }
  __syncthreads();
  if (tid == 0){
    int s = 0;
    for (int w = 0; w < NWORDS; w++){ pk[w] = s; s += __popcll(keepv[w]); }
    Ktot = s;
    int su = 0;
    for (int w = 0; w < NWORDS; w++){
      unsigned long long pres = (w < NWORDS-1) ? ~0ull : ((1ull<<32) - 1ull);
      pu[w] = su; su += __popcll(pres & ~keepv[w]);
    }
  }
  __syncthreads();
  int K = Ktot;
  for (int i = tid; i < T_CAT; i += 256){
    int w = i >> 6, l = i & 63;
    unsigned long long kvw = keepv[w];
    bool kept = (kvw >> l) & 1ull;
    unsigned long long low = (l == 0) ? 0ull : ((1ull << l) - 1ull);
    int slot;
    if (kept) slot = pk[w] + __popcll(kvw & low);
    else {
      unsigned long long pres = (w < NWORDS-1) ? ~0ull : ((1ull<<32) - 1ull);
      slot = K + pu[w] + __popcll(pres & ~kvw & low);
    }
    if (slot < POST){
      float4 b = ((const float4*)sbox)[img*T_CAT + i];
      ((float4*)out)[img*POST + slot] = b;
      out[2*POST*4 + img*POST + slot] = kept ? sscore[img*T_CAT + i] : -__builtin_huge_valf();
    }
  }
}

// =================== host ===================
extern "C" void kernel_launch(void* const* d_in, const int* in_sizes, int n_in,
                              void* d_out, int out_size, void* d_ws, size_t ws_size,
                              hipStream_t stream)
{
  const float* feats[5];
  for (int i = 0; i < 5; i++) feats[i] = (const float*)d_in[i];
  const float* w_conv  = (const float*)d_in[5];
  const float* b_conv  = (const float*)d_in[6];
  const float* w_obj   = (const float*)d_in[7];
  const float* b_obj   = (const float*)d_in[8];
  const float* w_delta = (const float*)d_in[9];
  const float* b_delta = (const float*)d_in[10];

  char* ws = (char*)d_ws;
  size_t off = 0;
  auto alloc = [&](size_t bytes)->char*{ char* r = ws + off; off += (bytes + 255) & ~(size_t)255; return r; };
  float*    wt         = (float*)   alloc(256*256*9*4);
  float*    scores_ws  = (float*)   alloc((size_t)2*SC_TOT*4);
  float*    boxes_ws   = (float*)   alloc((size_t)2*SC_TOT*16);
  float*    cat_scores = (float*)   alloc((size_t)2*T_CAT*4);
  unsigned* cat_u      = (unsigned*)alloc((size_t)2*T_CAT*4);
  float*    cat_boxes  = (float*)   alloc((size_t)2*T_CAT*16);
  float*    sscore     = (float*)   alloc((size_t)2*T_CAT*4);
  float*    sbox       = (float*)   alloc((size_t)2*T_CAT*16);
  float*    soff_b     = (float*)   alloc((size_t)2*T_CAT*16);
  int*      svalid     = (int*)     alloc((size_t)2*T_CAT*4);
  unsigned long long* mask = (unsigned long long*)alloc((size_t)2*T_CAT*NWORDS*8);
  unsigned* ghist      = (unsigned*)alloc(4*10*256*4);
  int*      meta       = (int*)     alloc(256);
  unsigned long long* selg = (unsigned long long*)alloc(10*1024*8);
  unsigned* tieg       = (unsigned*)alloc(10*1024*4);
  int*      cnts       = (int*)     alloc(256);
  // MFMA-path scratch
  _Float16* Xh  = (_Float16*)alloc((size_t)TOTG*8*2);
  short*    Xl  = (short*)   alloc((size_t)TOTG*8*2);
  _Float16* Whg = (_Float16*)alloc((size_t)256*256*9*2);
  short*    Wlg = (short*)   alloc((size_t)256*256*9*2);
  bool big = (ws_size >= off);
  (void)in_sizes; (void)n_in; (void)out_size;

  kzero<<<40, 256, 0, stream>>>(ghist, cnts, meta);

  if (big){
    // level params
    static const int Hps[5]={258,130,66,34,18}, Hs[5]={256,128,64,32,16};
    static const int Cs[5]={64,64,64,32,16}, lcs[5]={6,6,6,5,4};
    static const int lxts[5]={2,1,0,0,0}, Rs[5]={2,2,2,4,8};
    static const int TRs[5]={4,4,4,6,10}, CPs[5]={66,66,66,34,18};
    static const int ltpis[5]={9,7,5,3,1};
    static const int aoffs[5]={0,196608,245760,258048,261120};
    static const float strides[5]={4.f,8.f,16.f,32.f,64.f};
    static const float sizes[5]={32.f,64.f,128.f,256.f,512.f};
    CAll ca; XPar xp;
    int gacc = 0, bacc = 0;
    for (int l = 0; l < 5; l++){
      CLP& p = ca.l[l];
      p.Hp = Hps[l]; p.Wp = Hps[l]; p.H = Hs[l]; p.W = Hs[l];
      p.C = Cs[l]; p.lcC = lcs[l]; p.lxt = lxts[l];
      p.xtm1 = (Hs[l]/Cs[l]) - 1; p.R = Rs[l]; p.TR = TRs[l]; p.CP = CPs[l];
      p.TRCP = TRs[l]*CPs[l]; p.tpim1 = (1<<ltpis[l]) - 1; p.ltpi = ltpis[l];
      p.aoff = aoffs[l]; p.goff = gacc;
      p.stride = strides[l];
      float area = sizes[l]*sizes[l];
      float r0 = sqrtf(area/0.5f), r1 = sqrtf(area/1.0f), r2 = sqrtf(area/2.0f);
      p.aw0 = r0; p.aw1 = r1; p.aw2 = r2;
      p.ah0 = r0*0.5f; p.ah1 = r1*1.0f; p.ah2 = r2*2.0f;
      ca.pref[l] = bacc;
      xp.goff[l] = gacc;
      xp.HpWp[l] = Hps[l]*Hps[l]; xp.Wp[l] = Hps[l]; xp.H[l] = Hs[l]; xp.W[l] = Hs[l];
      gacc += 2*32*Hps[l]*Hps[l];
      bacc += ((Hs[l]*Hs[l])/128)*2;
    }
    ca.pref[5] = bacc; xp.goff[5] = gacc;

    kwprep<<<(256*256*9 + 255)/256, 256, 0, stream>>>(w_conv, Whg, Wlg);
    kxprep<<<(TOTG + 255)/256, 256, 0, stream>>>(feats[0],feats[1],feats[2],feats[3],feats[4], Xh, Xl, xp);
    kmf<<<bacc, 256, 0, stream>>>(Xh, Xl, Whg, Wlg, b_conv, w_obj, b_obj, w_delta, b_delta,
                                  scores_ws, boxes_ws, ca);
  } else {
    kwt<<<(256*256*9 + 255)/256, 256, 0, stream>>>(w_conv, wt);
    struct Lv { int H, W, TP, aoff; float size, stride; };
    static const Lv LV[5] = {
      {256,256,64, 0,      32.f,  4.f},
      {128,128,32, 196608, 64.f,  8.f},
      {64, 64, 16, 245760, 128.f, 16.f},
      {32, 32, 16, 258048, 256.f, 32.f},
      {16, 16, 16, 261120, 512.f, 64.f},
    };
    const float ratios[3] = {0.5f, 1.0f, 2.0f};
    for (int l = 0; l < 5; l++){
      float area = LV[l].size * LV[l].size;
      float aw[3], ah[3];
      for (int a = 0; a < 3; a++){ aw[a] = sqrtf(area / ratios[a]); ah[a] = aw[a] * ratios[a]; }
      dim3 grid(LV[l].W / LV[l].TP, LV[l].H, 2);
      if (LV[l].TP == 64)
        kconv<64><<<grid, 256, 0, stream>>>(feats[l], wt, b_conv, w_obj, b_obj, w_delta, b_delta,
          scores_ws, boxes_ws, LV[l].H, LV[l].W, LV[l].aoff, LV[l].stride,
          aw[0],aw[1],aw[2], ah[0],ah[1],ah[2]);
      else if (LV[l].TP == 32)
        kconv<32><<<grid, 256, 0, stream>>>(feats[l], wt, b_conv, w_obj, b_obj, w_delta, b_delta,
          scores_ws, boxes_ws, LV[l].H, LV[l].W, LV[l].aoff, LV[l].stride,
          aw[0],aw[1],aw[2], ah[0],ah[1],ah[2]);
      else
        kconv<16><<<grid, 256, 0, stream>>>(feats[l], wt, b_conv, w_obj, b_obj, w_delta, b_delta,
          scores_ws, boxes_ws, LV[l].H, LV[l].W, LV[l].aoff, LV[l].stride,
          aw[0],aw[1],aw[2], ah[0],ah[1],ah[2]);
    }
  }

  for (int pass = 0; pass < 4; pass++){
    khist<<<dim3(32,10), 256, 0, stream>>>(scores_ws, ghist, meta, pass);
    kscan<<<1, 64, 0, stream>>>(ghist, meta, pass);
  }
  kselect<<<dim3(32,10), 256, 0, stream>>>(scores_ws, meta, selg, tieg, cnts);
  ksort<<<10, 1024, 0, stream>>>(scores_ws, boxes_ws, selg, tieg, cnts, meta,
                                 cat_scores, cat_u, cat_boxes);
  krank<<<dim3((T_CAT+255)/256, 2), 256, 0, stream>>>(cat_scores, cat_u, cat_boxes,
                                                      sscore, sbox, soff_b, svalid);
  kiou<<<dim3(NWORDS, 2), 256, 0, stream>>>(soff_b, mask);
  knms<<<2, 256, 0, stream>>>(mask, svalid, sscore, sbox, (float*)d_out);
}

// Round 4
// 2154.300 us; speedup vs baseline: 3.8352x; 1.4053x over previous
//
#include <hip/hip_runtime.h>
#include <hip/hip_fp16.h>
#include <math.h>

#define SC_TOT   261888
#define T_CAT    4768
#define NWORDS   75
#define POST     1000
#define IMG_F    1024.0f
#define SCALE_CLAMP_F 4.135166556742356f
#define TOTG     5715200

typedef _Float16 half8 __attribute__((ext_vector_type(8)));
typedef short   short8 __attribute__((ext_vector_type(8)));
typedef float  floatx4 __attribute__((ext_vector_type(4)));

__device__ __forceinline__ unsigned ufloat(float f){
  unsigned b = __float_as_uint(f);
  return (b & 0x80000000u) ? ~b : (b | 0x80000000u);
}
__device__ __forceinline__ short f2bf_rne(float f){
  unsigned u = __float_as_uint(f);
  u += 0x7FFFu + ((u>>16)&1u);
  return (short)(u>>16);
}
// f16x8 -> bf16x8 (truncating; feeds 2^-12-scale correction terms)
__device__ __forceinline__ short8 h2b(half8 h){
  union { half8 v; unsigned u[4]; } a; a.v = h;
  union { short8 v; unsigned u[4]; } r;
  #pragma unroll
  for (int i=0;i<4;i++){
    unsigned w = a.u[i];
    __half2 p = *reinterpret_cast<__half2*>(&w);
    float f0 = __low2float(p), f1 = __high2float(p);
    r.u[i] = __byte_perm(__float_as_uint(f0), __float_as_uint(f1), 0x7632);
  }
  return r.v;
}

__device__ const int d_aoff[5]   = {0, 196608, 245760, 258048, 261120};
__device__ const int d_M[5]      = {196608, 49152, 12288, 3072, 768};
__device__ const int d_K[5]      = {1000, 1000, 1000, 1000, 768};
__device__ const int d_catoff[5] = {0, 1000, 2000, 3000, 4000};

// =================== pre-pass: weight split into A-frag layout ===================
__global__ void kwprep(const float* __restrict__ wsrc, _Float16* __restrict__ Whg, short* __restrict__ Wlg){
  int i = blockIdx.x*256 + threadIdx.x;
  if (i >= 256*256*9) return;
  int c8 = i&7, o = (i>>3)&255, kq = (i>>11)&3, rest = i>>13;
  int s = rest % 9, cc = rest / 9;
  int c = cc*32 + kq*8 + c8;
  float w = wsrc[(o*256 + c)*9 + s];
  _Float16 h = (_Float16)w;
  Whg[i] = h;
  Wlg[i] = f2bf_rne(w - (float)h);
}

// =================== pre-pass: X split into padded canvases ===================
struct XPar { int goff[6]; int HpWp[5]; int Wp[5]; int H[5]; int W[5]; };
__global__ void kxprep(const float* __restrict__ f0, const float* __restrict__ f1,
                       const float* __restrict__ f2, const float* __restrict__ f3,
                       const float* __restrict__ f4,
                       _Float16* __restrict__ Xh, short* __restrict__ Xl, XPar P)
{
  int gid = blockIdx.x*256 + threadIdx.x;
  if (gid >= TOTG) return;
  int lvl = 0;
  #pragma unroll
  for (int i=1;i<5;i++) if (gid >= P.goff[i]) lvl = i;
  int rem = gid - P.goff[lvl];
  int HpWp = P.HpWp[lvl], Wp = P.Wp[lvl], H = P.H[lvl], W = P.W[lvl];
  int n = rem / (HpWp*32); rem -= n*HpWp*32;
  int cg = rem / HpWp;     rem -= cg*HpWp;
  int y = rem / Wp;        int x = rem - y*Wp;
  const float* f = (lvl==0)?f0:(lvl==1)?f1:(lvl==2)?f2:(lvl==3)?f3:f4;
  bool inter = (x>=1) && (x<=W) && (y>=1) && (y<=H);
  long long base = inter ? (((long long)(n*256 + cg*8)*H + (y-1))*W + (x-1)) : 0;
  long long chs = (long long)H*W;
  half8 h; short8 l;
  #pragma unroll
  for (int c8=0;c8<8;c8++){
    float v = inter ? f[base + (long long)c8*chs] : 0.f;
    _Float16 hh = (_Float16)v;
    h[c8] = hh;
    l[c8] = f2bf_rne(v - (float)hh);
  }
  *(half8*)(Xh + (long long)gid*8) = h;
  *(short8*)(Xl + (long long)gid*8) = l;
}

// =================== unified MFMA conv + heads + decode ===================
struct CLP {
  int Hp, Wp, H, W, C, lcC, lxt, xtm1, R, TR, CP, TRCP, tpim1, ltpi, aoff, goff;
  float stride, aw0, aw1, aw2, ah0, ah1, ah2;
};
struct CAll { CLP l[5]; int pref[6]; };

__global__ __launch_bounds__(256, 2) void kmf(
  const _Float16* __restrict__ Xh, const short* __restrict__ Xl,
  const _Float16* __restrict__ Whg, const short* __restrict__ Wlg,
  const float* __restrict__ b_conv, const float* __restrict__ w_obj, const float* __restrict__ b_obj,
  const float* __restrict__ w_delta, const float* __restrict__ b_delta,
  float* __restrict__ scores_ws, float* __restrict__ boxes_ws, CAll A)
{
  __shared__ float whead_s[3840];
  __shared__ float bconv_s[256];
  __shared__ __align__(16) char uni[33792];
  _Float16* XT_h = (_Float16*)uni;
  short*    XT_l = (short*)(uni + 16896);
  float*    hb2  = (float*)uni;

  const int tid  = threadIdx.x;
  const int wv   = tid >> 6;
  const int lane = tid & 63;
  const int l15  = lane & 15;
  const int kq   = lane >> 4;

  int lvl = 0;
  #pragma unroll
  for (int i=1;i<5;i++) if ((int)blockIdx.x >= A.pref[i]) lvl = i;
  const CLP P = A.l[lvl];
  int bl = blockIdx.x - A.pref[lvl];
  int n  = bl >> P.ltpi;
  int t  = bl & P.tpim1;
  int y0 = (t >> P.lxt) * P.R;
  int x0 = (t & P.xtm1) * P.C;

  for (int i = tid; i < 3840; i += 256) whead_s[i] = (i < 768) ? w_obj[i] : w_delta[i-768];
  bconv_s[tid] = b_conv[tid];

  floatx4 acc[4][8];
  #pragma unroll
  for (int mt=0;mt<4;mt++)
    #pragma unroll
    for (int nt=0;nt<8;nt++) acc[mt][nt] = (floatx4){0.f,0.f,0.f,0.f};

  const int TRCP = P.TRCP, CP = P.CP, TR = P.TR;
  const int U = 4*TRCP;

  for (int cc = 0; cc < 8; cc++){
    __syncthreads();
    for (int u = tid; u < U; u += 256){
      int kqs = u / TRCP;
      int rem = u - kqs*TRCP;
      int r   = rem / CP;
      int col = rem - r*CP;
      int src = P.goff + ((n*32 + cc*4 + kqs)*P.Hp + y0 + r)*P.Wp + x0 + col;
      *(uint4*)((char*)XT_h + u*16) = *(const uint4*)(Xh + (long long)src*8);
      *(uint4*)((char*)XT_l + u*16) = *(const uint4*)(Xl + (long long)src*8);
    }
    __syncthreads();

    for (int s = 0; s < 9; s++){
      int ky = s / 3, kx = s - ky*3;
      int wb = (((cc*9 + s)*4 + kq)*256) + 64*wv + l15;
      half8 ah[4]; short8 al[4], ahb[4];
      #pragma unroll
      for (int mt=0;mt<4;mt++){
        ah[mt]  = *(const half8*)(Whg + (long long)(wb + 16*mt)*8);
        al[mt]  = *(const short8*)(Wlg + (long long)(wb + 16*mt)*8);
        ahb[mt] = h2b(ah[mt]);
      }
      int rowbase = kq*TR + ky;
      #pragma unroll
      for (int nh=0;nh<2;nh++){
        half8 bh[4]; short8 bl[4], bhb[4];
        #pragma unroll
        for (int q=0;q<4;q++){
          int px  = (nh*4+q)*16 + l15;
          int r   = px >> P.lcC;
          int col = px & (P.C-1);
          int gi  = (rowbase + r)*CP + col + kx;
          bh[q]  = *(const half8*)((char*)XT_h + gi*16);
          bl[q]  = *(const short8*)((char*)XT_l + gi*16);
          bhb[q] = h2b(bh[q]);
        }
        #pragma unroll
        for (int mt=0;mt<4;mt++)
          #pragma unroll
          for (int q=0;q<4;q++){
            int nt = nh*4+q;
            acc[mt][nt] = __builtin_amdgcn_mfma_f32_16x16x32_f16 (ah[mt],  bh[q],  acc[mt][nt], 0,0,0);
            acc[mt][nt] = __builtin_amdgcn_mfma_f32_16x16x32_bf16(ahb[mt], bl[q],  acc[mt][nt], 0,0,0);
            acc[mt][nt] = __builtin_amdgcn_mfma_f32_16x16x32_bf16(al[mt],  bhb[q], acc[mt][nt], 0,0,0);
          }
      }
    }
  }

  #pragma unroll
  for (int mt=0;mt<4;mt++){
    floatx4 bc = *(const floatx4*)(bconv_s + 64*wv + 16*mt + 4*kq);
    #pragma unroll
    for (int nt=0;nt<8;nt++)
      #pragma unroll
      for (int e=0;e<4;e++){
        float v = acc[mt][nt][e] + bc[e];
        acc[mt][nt][e] = v > 0.f ? v : 0.f;
      }
  }
  __syncthreads();

  #pragma unroll
  for (int nh=0;nh<2;nh++){
    float sjq[15][4];
    #pragma unroll
    for (int j=0;j<15;j++)
      #pragma unroll
      for (int q=0;q<4;q++) sjq[j][q] = 0.f;
    for (int j=0;j<15;j++){
      #pragma unroll
      for (int mt=0;mt<4;mt++){
        floatx4 w4 = *(const floatx4*)(whead_s + j*256 + 64*wv + 16*mt + 4*kq);
        #pragma unroll
        for (int q=0;q<4;q++){
          floatx4 t4 = acc[mt][nh*4+q];
          sjq[j][q] += w4[0]*t4[0] + w4[1]*t4[1] + w4[2]*t4[2] + w4[3]*t4[3];
        }
      }
    }
    #pragma unroll
    for (int j=0;j<15;j++)
      #pragma unroll
      for (int q=0;q<4;q++){
        float v = sjq[j][q];
        v += __shfl_xor(v, 16);
        v += __shfl_xor(v, 32);
        if (kq == 0) hb2[(wv*15 + j)*128 + (nh*4+q)*16 + l15] = v;
      }
  }
  __syncthreads();

  for (int idx = tid; idx < 3*128; idx += 256){
    int a  = idx % 3;
    int px = idx / 3;
    int y = y0 + (px >> P.lcC);
    int x = x0 + (px & (P.C-1));
    float sc  = b_obj[a];
    float dx  = b_delta[a*4+0], dyv = b_delta[a*4+1];
    float dw  = b_delta[a*4+2], dh  = b_delta[a*4+3];
    #pragma unroll
    for (int w=0; w<4; w++){
      sc  += hb2[(w*15 + a)*128 + px];
      dx  += hb2[(w*15 + 3 + a*4+0)*128 + px];
      dyv += hb2[(w*15 + 3 + a*4+1)*128 + px];
      dw  += hb2[(w*15 + 3 + a*4+2)*128 + px];
      dh  += hb2[(w*15 + 3 + a*4+3)*128 + px];
    }
    float aw  = (a==0)?P.aw0:((a==1)?P.aw1:P.aw2);
    float ahh = (a==0)?P.ah0:((a==1)?P.ah1:P.ah2);
    float gx = (float)x * P.stride, gy = (float)y * P.stride;
    float pcx = dx*aw + gx, pcy = dyv*ahh + gy;
    float pw = expf(fminf(dw, SCALE_CLAMP_F))*aw;
    float ph = expf(fminf(dh, SCALE_CLAMP_F))*ahh;
    float x1 = fminf(fmaxf(pcx - 0.5f*pw, 0.f), IMG_F);
    float y1 = fminf(fmaxf(pcy - 0.5f*ph, 0.f), IMG_F);
    float x2 = fminf(fmaxf(pcx + 0.5f*pw, 0.f), IMG_F);
    float y2 = fminf(fmaxf(pcy + 0.5f*ph, 0.f), IMG_F);
    long long ai = (long long)n*SC_TOT + P.aoff + (long long)(y*P.W + x)*3 + a;
    scores_ws[ai] = sc;
    ((float4*)boxes_ws)[ai] = make_float4(x1,y1,x2,y2);
  }
}

// =================== fallback fp32 conv (round-2 path) ===================
__global__ void kwt(const float* __restrict__ w_conv, float* __restrict__ wt){
  int i = blockIdx.x*256 + threadIdx.x;
  if (i < 256*256*9){
    int j = i & 3; int t = i >> 2;
    int ol = t & 63; int t2 = t >> 6;
    int k = t2 % 9; int c = t2 / 9;
    int o = j*64 + ol;
    wt[i] = w_conv[(o*256 + c)*9 + k];
  }
}

template<int TP>
__global__ __launch_bounds__(256, 3) void kconv(
    const float* __restrict__ f, const float* __restrict__ wtt, const float* __restrict__ b_conv,
    const float* __restrict__ w_obj, const float* __restrict__ b_obj,
    const float* __restrict__ w_delta, const float* __restrict__ b_delta,
    float* __restrict__ scores_ws, float* __restrict__ boxes_ws,
    int H, int W, int aoff, float fstride,
    float aw0, float aw1, float aw2, float ah0, float ah1, float ah2)
{
  constexpr int PXT = TP/4;
  constexpr int XSS = TP + 8;
  constexpr int TLS = TP + 1;
  __shared__ float xs[2][3*XSS];
  __shared__ float t_lds[64*TLS];
  __shared__ float hb[16*TP];

  const int tid = threadIdx.x;
  const int w0 = blockIdx.x * TP;
  const int h  = blockIdx.y;
  const int n  = blockIdx.z;
  const int ol = tid >> 2;
  const int pg = tid & 3;
  const int px0 = pg * PXT;

  float acc[4][PXT];
  #pragma unroll
  for (int j = 0; j < 4; j++)
    #pragma unroll
    for (int p = 0; p < PXT; p++) acc[j][p] = 0.f;

  const int NSTG = 3*(TP+2);
  int sdy = tid / (TP+2), sdx = tid % (TP+2);
  int sy = h - 1 + sdy, sx = w0 - 1 + sdx;
  bool sthr = (tid < NSTG);
  bool sok = sthr && sy >= 0 && sy < H && sx >= 0 && sx < W;
  const long long fbase = (long long)n*256*H*W;
  long long soff_i = (long long)sy*W + sx;

  if (sthr) xs[0][sdy*XSS + sdx] = sok ? f[fbase + soff_i] : 0.f;
  __syncthreads();

  const float4* wt4 = (const float4*)wtt;

  for (int c = 0; c < 256; c++){
    float gx = 0.f;
    if (c < 255 && sthr) gx = sok ? f[fbase + (long long)(c+1)*H*W + soff_i] : 0.f;

    float4 wq[9];
    #pragma unroll
    for (int k = 0; k < 9; k++) wq[k] = wt4[(c*9 + k)*64 + ol];

    const float* xb = &xs[c & 1][0];
    #pragma unroll
    for (int dy = 0; dy < 3; dy++){
      const float* row = xb + dy*XSS + px0;
      float xr[PXT+2];
      #pragma unroll
      for (int t = 0; t < PXT; t += 4){
        float4 q = *(const float4*)(row + t);
        xr[t]=q.x; xr[t+1]=q.y; xr[t+2]=q.z; xr[t+3]=q.w;
      }
      xr[PXT]   = row[PXT];
      xr[PXT+1] = row[PXT+1];
      float4 qa = wq[3*dy], qb = wq[3*dy+1], qc = wq[3*dy+2];
      float wa[4] = {qa.x, qa.y, qa.z, qa.w};
      float wb[4] = {qb.x, qb.y, qb.z, qb.w};
      float wc[4] = {qc.x, qc.y, qc.z, qc.w};
      #pragma unroll
      for (int j = 0; j < 4; j++)
        #pragma unroll
        for (int pp = 0; pp < PXT; pp++)
          acc[j][pp] += wa[j]*xr[pp] + wb[j]*xr[pp+1] + wc[j]*xr[pp+2];
    }

    if (c < 255 && sthr) xs[(c+1)&1][sdy*XSS + sdx] = gx;
    __syncthreads();
  }

  #pragma unroll
  for (int j = 0; j < 4; j++){
    float bc = b_conv[j*64 + ol];
    #pragma unroll
    for (int p = 0; p < PXT; p++){ float v = acc[j][p] + bc; acc[j][p] = v > 0.f ? v : 0.f; }
  }

  constexpr int G = 256 / TP;
  constexpr int HPT = (15 + G - 1) / G;
  const int p = tid & (TP-1);
  const int g = tid / TP;
  const float* wj[HPT];
  int jidx[HPT];
  float hacc[HPT];
  #pragma unroll
  for (int q = 0; q < HPT; q++){
    int j = g*HPT + q;
    jidx[q] = j;
    hacc[q] = 0.f;
    wj[q] = (j < 3) ? (w_obj + j*256) : ((j < 15) ? (w_delta + (j-3)*256) : w_obj);
  }
  for (int quarter = 0; quarter < 4; quarter++){
    __syncthreads();
    #pragma unroll
    for (int px = 0; px < PXT; px++) t_lds[ol*TLS + px0 + px] = acc[quarter][px];
    __syncthreads();
    for (int oo = 0; oo < 64; oo++){
      float tv = t_lds[oo*TLS + p];
      int ob = quarter*64 + oo;
      #pragma unroll
      for (int q = 0; q < HPT; q++) hacc[q] += wj[q][ob] * tv;
    }
  }
  #pragma unroll
  for (int q = 0; q < HPT; q++){
    int j = jidx[q];
    if (j < 15){
      float bias = (j < 3) ? b_obj[j] : b_delta[j-3];
      hb[j*TP + p] = hacc[q] + bias;
    }
  }
  __syncthreads();

  if (tid < 3*TP){
    int a = tid % 3, pp = tid / 3;
    float score = hb[a*TP + pp];
    float dx  = hb[(3 + a*4 + 0)*TP + pp];
    float dyv = hb[(3 + a*4 + 1)*TP + pp];
    float dw  = hb[(3 + a*4 + 2)*TP + pp];
    float dh  = hb[(3 + a*4 + 3)*TP + pp];
    float aw = (a==0)?aw0:((a==1)?aw1:aw2);
    float ah = (a==0)?ah0:((a==1)?ah1:ah2);
    float gx = (float)(w0 + pp) * fstride;
    float gy = (float)h * fstride;
    float pcx = dx*aw + gx;
    float pcy = dyv*ah + gy;
    float pw = expf(fminf(dw, SCALE_CLAMP_F))*aw;
    float ph = expf(fminf(dh, SCALE_CLAMP_F))*ah;
    float x1 = pcx - 0.5f*pw, y1 = pcy - 0.5f*ph;
    float x2 = pcx + 0.5f*pw, y2 = pcy + 0.5f*ph;
    x1 = fminf(fmaxf(x1, 0.f), IMG_F); y1 = fminf(fmaxf(y1, 0.f), IMG_F);
    x2 = fminf(fmaxf(x2, 0.f), IMG_F); y2 = fminf(fmaxf(y2, 0.f), IMG_F);
    long long ai = (long long)n*SC_TOT + aoff + (long long)(h*W + w0 + pp)*3 + a;
    scores_ws[ai] = score;
    ((float4*)boxes_ws)[ai] = make_float4(x1, y1, x2, y2);
  }
}

// -------------------- zero scratch --------------------
__global__ void kzero(unsigned* ghist, int* cnts, int* meta){
  int i = blockIdx.x*256 + threadIdx.x;
  if (i < 4*10*256) ghist[i] = 0u;
  if (i < 32){ cnts[i] = 0; meta[i] = 0; }
}

// -------------------- radix-select --------------------
__global__ __launch_bounds__(256) void khist(const float* __restrict__ scores_ws,
    unsigned* __restrict__ ghist, const int* __restrict__ meta, int pass)
{
  int seg = blockIdx.y; int img = seg/5, lvl = seg%5;
  int M = d_M[lvl];
  const float* sc = scores_ws + (long long)img*SC_TOT + d_aoff[lvl];
  __shared__ unsigned h[256];
  h[threadIdx.x] = 0u;
  __syncthreads();
  int shift = 24 - 8*pass;
  unsigned prefix = (pass > 0) ? ((const unsigned*)meta)[seg*2] : 0u;
  unsigned pmask  = (pass > 0) ? (0xFFFFFFFFu << (shift+8)) : 0u;
  int chunk = (M + (int)gridDim.x - 1) / (int)gridDim.x;
  int lo = blockIdx.x*chunk, hiI = min(lo+chunk, M);
  for (int i = lo + threadIdx.x; i < hiI; i += 256){
    unsigned u = ufloat(sc[i]);
    if (((u ^ prefix) & pmask) == 0u) atomicAdd(&h[(u>>shift)&255u], 1u);
  }
  __syncthreads();
  unsigned* gh = ghist + (pass*10 + seg)*256;
  if (h[threadIdx.x]) atomicAdd(&gh[threadIdx.x], h[threadIdx.x]);
}

__global__ void kscan(const unsigned* __restrict__ ghist, int* meta, int pass){
  int seg = threadIdx.x;
  if (seg < 10){
    int lvl = seg % 5; int k = d_K[lvl];
    unsigned prefix = 0u; int rem = k;
    if (pass > 0){ prefix = ((unsigned*)meta)[seg*2]; rem = meta[seg*2+1]; }
    const unsigned* h = ghist + (pass*10+seg)*256;
    int shift = 24 - 8*pass;
    int r = rem; int b = 0;
    for (int x = 255; x >= 0; x--){
      int c = (int)h[x];
      if (c >= r){ b = x; break; }
      r -= c;
    }
    ((unsigned*)meta)[seg*2] = prefix | ((unsigned)b << shift);
    meta[seg*2+1] = r;
  }
}

__global__ __launch_bounds__(256) void kselect(const float* __restrict__ scores_ws,
    const int* __restrict__ meta, unsigned long long* __restrict__ selg,
    unsigned* __restrict__ tieg, int* __restrict__ cnts)
{
  int seg = blockIdx.y; int img = seg/5, lvl = seg%5;
  int M = d_M[lvl];
  const float* sc = scores_ws + (long long)img*SC_TOT + d_aoff[lvl];
  unsigned ut = ((const unsigned*)meta)[seg*2];
  int chunk = (M + (int)gridDim.x - 1) / (int)gridDim.x;
  int lo = blockIdx.x*chunk, hiI = min(lo+chunk, M);
  for (int i = lo + threadIdx.x; i < hiI; i += 256){
    unsigned u = ufloat(sc[i]);
    if (u > ut){
      int pp = atomicAdd(&cnts[seg*2], 1);
      if (pp < 1024) selg[seg*1024 + pp] = ((unsigned long long)u << 32) | (unsigned)(~(unsigned)i);
    } else if (u == ut){
      int pp = atomicAdd(&cnts[seg*2+1], 1);
      if (pp < 1024) tieg[seg*1024 + pp] = (unsigned)i;
    }
  }
}

__device__ __forceinline__ void bitonic_u32_asc(unsigned* a, int tid){
  for (int k2 = 2; k2 <= 1024; k2 <<= 1)
    for (int j = k2>>1; j > 0; j >>= 1){
      int ixj = tid ^ j;
      if (ixj > tid){
        unsigned A = a[tid], B = a[ixj];
        bool up = ((tid & k2) == 0);
        if (up ? (A > B) : (A < B)){ a[tid] = B; a[ixj] = A; }
      }
      __syncthreads();
    }
}
__device__ __forceinline__ void bitonic_u64_desc(unsigned long long* a, int tid){
  for (int k2 = 2; k2 <= 1024; k2 <<= 1)
    for (int j = k2>>1; j > 0; j >>= 1){
      int ixj = tid ^ j;
      if (ixj > tid){
        unsigned long long A = a[tid], B = a[ixj];
        bool up = ((tid & k2) == 0);
        if (up ? (A < B) : (A > B)){ a[tid] = B; a[ixj] = A; }
      }
      __syncthreads();
    }
}

__global__ __launch_bounds__(1024) void ksort(const float* __restrict__ scores_ws,
    const float* __restrict__ boxes_ws, const unsigned long long* __restrict__ selg,
    const unsigned* __restrict__ tieg, const int* __restrict__ cnts, const int* __restrict__ meta,
    float* __restrict__ cat_scores, unsigned* __restrict__ cat_u, float* __restrict__ cat_boxes)
{
  int seg = blockIdx.x; int img = seg/5, lvl = seg%5;
  int k = d_K[lvl];
  unsigned ut = ((const unsigned*)meta)[seg*2];
  int cg = cnts[seg*2];
  int ct = min(cnts[seg*2+1], 1024);
  __shared__ unsigned long long sb[1024];
  __shared__ unsigned tb[1024];
  int tid = threadIdx.x;
  tb[tid] = (tid < ct) ? tieg[seg*1024 + tid] : 0xFFFFFFFFu;
  __syncthreads();
  bitonic_u32_asc(tb, tid);
  unsigned long long v = 0ull;
  if (tid < cg && tid < 1024) v = selg[seg*1024 + tid];
  else if (tid >= cg && tid < k) v = ((unsigned long long)ut << 32) | (unsigned)(~tb[tid - cg]);
  sb[tid] = v;
  __syncthreads();
  bitonic_u64_desc(sb, tid);
  if (tid < k){
    unsigned long long e = sb[tid];
    unsigned idx = ~(unsigned)e;
    unsigned u = (unsigned)(e >> 32);
    int pos = d_catoff[lvl] + tid;
    long long src = (long long)img*SC_TOT + d_aoff[lvl] + idx;
    cat_scores[img*T_CAT + pos] = scores_ws[src];
    cat_u[img*T_CAT + pos] = u;
    ((float4*)cat_boxes)[img*T_CAT + pos] = ((const float4*)boxes_ws)[src];
  }
}

__device__ __forceinline__ int cnt_gt_desc(const unsigned* a, int len, unsigned u){
  int lo=0, hi=len;
  while (lo<hi){ int m=(lo+hi)>>1; if (a[m] > u) lo=m+1; else hi=m; }
  return lo;
}
__device__ __forceinline__ int cnt_ge_desc(const unsigned* a, int len, unsigned u){
  int lo=0, hi=len;
  while (lo<hi){ int m=(lo+hi)>>1; if (a[m] >= u) lo=m+1; else hi=m; }
  return lo;
}

__global__ void krank(const float* __restrict__ cat_scores, const unsigned* __restrict__ cat_u,
    const float* __restrict__ cat_boxes, float* __restrict__ sscore, float* __restrict__ sbox,
    float* __restrict__ soff, int* __restrict__ svalid)
{
  int img = blockIdx.y;
  int pos = blockIdx.x*256 + threadIdx.x;
  if (pos >= T_CAT) return;
  const unsigned* cu = cat_u + img*T_CAT;
  int lvl = pos / 1000; if (lvl > 4) lvl = 4;
  unsigned u = cu[pos];
  int rank = pos - d_catoff[lvl];
  #pragma unroll
  for (int l2 = 0; l2 < 5; l2++){
    if (l2 == lvl) continue;
    const unsigned* segp = cu + d_catoff[l2];
    int len = d_K[l2];
    rank += (l2 < lvl) ? cnt_ge_desc(segp, len, u) : cnt_gt_desc(segp, len, u);
  }
  float s = cat_scores[img*T_CAT + pos];
  float4 b = ((const float4*)cat_boxes)[img*T_CAT + pos];
  sscore[img*T_CAT + rank] = s;
  ((float4*)sbox)[img*T_CAT + rank] = b;
  float of = (float)lvl * (IMG_F + 1.0f);
  ((float4*)soff)[img*T_CAT + rank] = make_float4(b.x+of, b.y+of, b.z+of, b.w+of);
  svalid[img*T_CAT + rank] = ((b.z - b.x > 0.0f) && (b.w - b.y > 0.0f)) ? 1 : 0;
}

// -------------------- IoU suppression bitmask (transposed: mkT[(img*NW+w)*T_CAT+row]) --------------------
__global__ __launch_bounds__(256) void kiou(const float* __restrict__ soff,
    unsigned long long* __restrict__ mkT)
{
  int rowt = blockIdx.x, img = blockIdx.y;
  int wv = threadIdx.x >> 6, lane = threadIdx.x & 63;
  const float4* sb4 = (const float4*)soff + (long long)img*T_CAT;
  for (int rr = 0; rr < 16; rr++){
    int row = rowt*64 + wv*16 + rr;
    if (row >= T_CAT) break;
    float4 rb = sb4[row];
    float rarea = (rb.z - rb.x)*(rb.w - rb.y);
    for (int w = 0; w < NWORDS; w++){
      int col = w*64 + lane;
      bool pred = false;
      if (col < T_CAT && col > row){
        float4 cb = sb4[col];
        float carea = (cb.z - cb.x)*(cb.w - cb.y);
        float ltx = fmaxf(rb.x, cb.x), lty = fmaxf(rb.y, cb.y);
        float rbx = fminf(rb.z, cb.z), rby = fminf(rb.w, cb.w);
        float wx = fmaxf(rbx - ltx, 0.f), wy = fmaxf(rby - lty, 0.f);
        float inter = wx*wy;
        float uni = rarea + carea - inter;
        float iou = (uni > 0.f) ? (inter/uni) : 0.f;
        pred = iou > 0.7f;
      }
      unsigned long long b = __ballot(pred);
      if (lane == 0) mkT[((long long)img*NWORDS + w)*T_CAT + row] = b;
    }
  }
}

// -------------------- greedy scan + finalize (transposed mask, parallel OR-reduce) --------------------
__global__ __launch_bounds__(256) void knms(const unsigned long long* __restrict__ mkT,
    const int* __restrict__ svalid, const float* __restrict__ sscore,
    const float* __restrict__ sbox, float* __restrict__ out)
{
  int img = blockIdx.x; int tid = threadIdx.x;
  int wv = tid >> 6, lane = tid & 63;
  __shared__ unsigned long long keep[NWORDS];
  __shared__ unsigned long long vb_s[NWORDS];
  __shared__ unsigned long long po_s[NWORDS*4];
  __shared__ unsigned long long keepv[NWORDS];
  __shared__ int pk[NWORDS], pu[NWORDS];
  __shared__ int Ktot;

  // init keep + valid bitmask via ballot
  for (int w = wv; w < NWORDS; w += 4){
    int row = w*64 + lane;
    bool v = (row < T_CAT) && (svalid[img*T_CAT + row] != 0);
    unsigned long long b = __ballot(v);
    if (lane == 0){ vb_s[w] = b; keep[w] = ~0ull; }
  }
  __syncthreads();

  const unsigned long long* mt = mkT + (long long)img*NWORDS*T_CAT;

  for (int w0 = 0; w0 < NWORDS; w0++){
    // all 4 waves redundantly finalize keep-word w0 (idempotent; benign race)
    int row = w0*64 + lane;
    unsigned long long m = (row < T_CAT) ? mt[(long long)w0*T_CAT + row] : 0ull;
    unsigned long long cur = keep[w0];
    #pragma unroll
    for (int l = 0; l < 64; l++){
      unsigned long long ml = __shfl(m, l);
      if ((cur >> l) & 1ull) cur &= ~ml;
    }
    if (cur == 0ull){           // block-uniform: nothing kept in this word
      if (tid == 0) keep[w0] = 0ull;
      continue;
    }
    if (tid == 0) keep[w0] = cur;
    // column update: 4 threads per later word, 16 rows each, vectorizable contiguous loads
    int t4 = tid & 3;
    int R = NWORDS - 1 - w0;
    for (int wi = tid >> 2; wi < R; wi += 64){
      int w = w0 + 1 + wi;
      const unsigned long long* colp = mt + (long long)w*T_CAT + w0*64 + t4*16;
      unsigned long long po = 0ull;
      #pragma unroll
      for (int j = 0; j < 16; j++){
        unsigned long long sel = ((cur >> (t4*16 + j)) & 1ull) ? ~0ull : 0ull;
        po |= colp[j] & sel;
      }
      po_s[wi*4 + t4] = po;
    }
    __syncthreads();
    for (int wi = tid; wi < R; wi += 256){
      int w = w0 + 1 + wi;
      unsigned long long s = po_s[wi*4] | po_s[wi*4+1] | po_s[wi*4+2] | po_s[wi*4+3];
      keep[w] &= ~s;
    }
    __syncthreads();
  }

  __syncthreads();
  for (int w = tid; w < NWORDS; w += 256){
    unsigned long long pres = (w < NWORDS-1) ? ~0ull : ((1ull << (T_CAT - 64*(NWORDS-1))) - 1ull);
    keepv[w] = keep[w] & pres & vb_s[w];
  }
  __syncthreads();
  if (tid == 0){
    int s = 0;
    for (int w = 0; w < NWORDS; w++){ pk[w] = s; s += __popcll(keepv[w]); }
    Ktot = s;
    int su = 0;
    for (int w = 0; w < NWORDS; w++){
      unsigned long long pres = (w < NWORDS-1) ? ~0ull : ((1ull<<32) - 1ull);
      pu[w] = su; su += __popcll(pres & ~keepv[w]);
    }
  }
  __syncthreads();
  int K = Ktot;
  for (int i = tid; i < T_CAT; i += 256){
    int w = i >> 6, l = i & 63;
    unsigned long long kvw = keepv[w];
    bool kept = (kvw >> l) & 1ull;
    unsigned long long low = (l == 0) ? 0ull : ((1ull << l) - 1ull);
    int slot;
    if (kept) slot = pk[w] + __popcll(kvw & low);
    else {
      unsigned long long pres = (w < NWORDS-1) ? ~0ull : ((1ull<<32) - 1ull);
      slot = K + pu[w] + __popcll(pres & ~kvw & low);
    }
    if (slot < POST){
      float4 b = ((const float4*)sbox)[img*T_CAT + i];
      ((float4*)out)[img*POST + slot] = b;
      out[2*POST*4 + img*POST + slot] = kept ? sscore[img*T_CAT + i] : -__builtin_huge_valf();
    }
  }
}

// =================== host ===================
extern "C" void kernel_launch(void* const* d_in, const int* in_sizes, int n_in,
                              void* d_out, int out_size, void* d_ws, size_t ws_size,
                              hipStream_t stream)
{
  const float* feats[5];
  for (int i = 0; i < 5; i++) feats[i] = (const float*)d_in[i];
  const float* w_conv  = (const float*)d_in[5];
  const float* b_conv  = (const float*)d_in[6];
  const float* w_obj   = (const float*)d_in[7];
  const float* b_obj   = (const float*)d_in[8];
  const float* w_delta = (const float*)d_in[9];
  const float* b_delta = (const float*)d_in[10];

  char* ws = (char*)d_ws;
  size_t off = 0;
  auto alloc = [&](size_t bytes)->char*{ char* r = ws + off; off += (bytes + 255) & ~(size_t)255; return r; };
  float*    wt         = (float*)   alloc(256*256*9*4);
  float*    scores_ws  = (float*)   alloc((size_t)2*SC_TOT*4);
  float*    boxes_ws   = (float*)   alloc((size_t)2*SC_TOT*16);
  float*    cat_scores = (float*)   alloc((size_t)2*T_CAT*4);
  unsigned* cat_u      = (unsigned*)alloc((size_t)2*T_CAT*4);
  float*    cat_boxes  = (float*)   alloc((size_t)2*T_CAT*16);
  float*    sscore     = (float*)   alloc((size_t)2*T_CAT*4);
  float*    sbox       = (float*)   alloc((size_t)2*T_CAT*16);
  float*    soff_b     = (float*)   alloc((size_t)2*T_CAT*16);
  int*      svalid     = (int*)     alloc((size_t)2*T_CAT*4);
  unsigned long long* mask = (unsigned long long*)alloc((size_t)2*NWORDS*T_CAT*8);
  unsigned* ghist      = (unsigned*)alloc(4*10*256*4);
  int*      meta       = (int*)     alloc(256);
  unsigned long long* selg = (unsigned long long*)alloc(10*1024*8);
  unsigned* tieg       = (unsigned*)alloc(10*1024*4);
  int*      cnts       = (int*)     alloc(256);
  _Float16* Xh  = (_Float16*)alloc((size_t)TOTG*8*2);
  short*    Xl  = (short*)   alloc((size_t)TOTG*8*2);
  _Float16* Whg = (_Float16*)alloc((size_t)256*256*9*2);
  short*    Wlg = (short*)   alloc((size_t)256*256*9*2);
  bool big = (ws_size >= off);
  (void)in_sizes; (void)n_in; (void)out_size;

  kzero<<<40, 256, 0, stream>>>(ghist, cnts, meta);

  if (big){
    static const int Hps[5]={258,130,66,34,18}, Hs[5]={256,128,64,32,16};
    static const int Cs[5]={64,64,64,32,16}, lcs[5]={6,6,6,5,4};
    static const int lxts[5]={2,1,0,0,0}, Rs[5]={2,2,2,4,8};
    static const int TRs[5]={4,4,4,6,10}, CPs[5]={66,66,66,34,18};
    static const int ltpis[5]={9,7,5,3,1};
    static const int aoffs[5]={0,196608,245760,258048,261120};
    static const float strides[5]={4.f,8.f,16.f,32.f,64.f};
    static const float sizes[5]={32.f,64.f,128.f,256.f,512.f};
    CAll ca; XPar xp;
    int gacc = 0, bacc = 0;
    for (int l = 0; l < 5; l++){
      CLP& p = ca.l[l];
      p.Hp = Hps[l]; p.Wp = Hps[l]; p.H = Hs[l]; p.W = Hs[l];
      p.C = Cs[l]; p.lcC = lcs[l]; p.lxt = lxts[l];
      p.xtm1 = (Hs[l]/Cs[l]) - 1; p.R = Rs[l]; p.TR = TRs[l]; p.CP = CPs[l];
      p.TRCP = TRs[l]*CPs[l]; p.tpim1 = (1<<ltpis[l]) - 1; p.ltpi = ltpis[l];
      p.aoff = aoffs[l]; p.goff = gacc;
      p.stride = strides[l];
      float area = sizes[l]*sizes[l];
      float r0 = sqrtf(area/0.5f), r1 = sqrtf(area/1.0f), r2 = sqrtf(area/2.0f);
      p.aw0 = r0; p.aw1 = r1; p.aw2 = r2;
      p.ah0 = r0*0.5f; p.ah1 = r1*1.0f; p.ah2 = r2*2.0f;
      ca.pref[l] = bacc;
      xp.goff[l] = gacc;
      xp.HpWp[l] = Hps[l]*Hps[l]; xp.Wp[l] = Hps[l]; xp.H[l] = Hs[l]; xp.W[l] = Hs[l];
      gacc += 2*32*Hps[l]*Hps[l];
      bacc += ((Hs[l]*Hs[l])/128)*2;
    }
    ca.pref[5] = bacc; xp.goff[5] = gacc;

    kwprep<<<(256*256*9 + 255)/256, 256, 0, stream>>>(w_conv, Whg, Wlg);
    kxprep<<<(TOTG + 255)/256, 256, 0, stream>>>(feats[0],feats[1],feats[2],feats[3],feats[4], Xh, Xl, xp);
    kmf<<<bacc, 256, 0, stream>>>(Xh, Xl, Whg, Wlg, b_conv, w_obj, b_obj, w_delta, b_delta,
                                  scores_ws, boxes_ws, ca);
  } else {
    kwt<<<(256*256*9 + 255)/256, 256, 0, stream>>>(w_conv, wt);
    struct Lv { int H, W, TP, aoff; float size, stride; };
    static const Lv LV[5] = {
      {256,256,64, 0,      32.f,  4.f},
      {128,128,32, 196608, 64.f,  8.f},
      {64, 64, 16, 245760, 128.f, 16.f},
      {32, 32, 16, 258048, 256.f, 32.f},
      {16, 16, 16, 261120, 512.f, 64.f},
    };
    const float ratios[3] = {0.5f, 1.0f, 2.0f};
    for (int l = 0; l < 5; l++){
      float area = LV[l].size * LV[l].size;
      float aw[3], ah[3];
      for (int a = 0; a < 3; a++){ aw[a] = sqrtf(area / ratios[a]); ah[a] = aw[a] * ratios[a]; }
      dim3 grid(LV[l].W / LV[l].TP, LV[l].H, 2);
      if (LV[l].TP == 64)
        kconv<64><<<grid, 256, 0, stream>>>(feats[l], wt, b_conv, w_obj, b_obj, w_delta, b_delta,
          scores_ws, boxes_ws, LV[l].H, LV[l].W, LV[l].aoff, LV[l].stride,
          aw[0],aw[1],aw[2], ah[0],ah[1],ah[2]);
      else if (LV[l].TP == 32)
        kconv<32><<<grid, 256, 0, stream>>>(feats[l], wt, b_conv, w_obj, b_obj, w_delta, b_delta,
          scores_ws, boxes_ws, LV[l].H, LV[l].W, LV[l].aoff, LV[l].stride,
          aw[0],aw[1],aw[2], ah[0],ah[1],ah[2]);
      else
        kconv<16><<<grid, 256, 0, stream>>>(feats[l], wt, b_conv, w_obj, b_obj, w_delta, b_delta,
          scores_ws, boxes_ws, LV[l].H, LV[l].W, LV[l].aoff, LV[l].stride,
          aw[0],aw[1],aw[2], ah[0],ah[1],ah[2]);
    }
  }

  for (int pass = 0; pass < 4; pass++){
    khist<<<dim3(32,10), 256, 0, stream>>>(scores_ws, ghist, meta, pass);
    kscan<<<1, 64, 0, stream>>>(ghist, meta, pass);
  }
  kselect<<<dim3(32,10), 256, 0, stream>>>(scores_ws, meta, selg, tieg, cnts);
  ksort<<<10, 1024, 0, stream>>>(scores_ws, boxes_ws, selg, tieg, cnts, meta,
                                 cat_scores, cat_u, cat_boxes);
  krank<<<dim3((T_CAT+255)/256, 2), 256, 0, stream>>>(cat_scores, cat_u, cat_boxes,
                                                      sscore, sbox, soff_b, svalid);
  kiou<<<dim3(NWORDS, 2), 256, 0, stream>>>(soff_b, mask);
  knms<<<2, 256, 0, stream>>>(mask, svalid, sscore, sbox, (float*)d_out);
}